// Round 3
// baseline (5592.738 us; speedup 1.0000x reference)
//
#include <hip/hip_runtime.h>
#include <math.h>

#define NL 28
#define DIM 1024
#define NHQ 16
#define NHKV 8
#define HDIM 128
#define NG 2
#define NFF 3072
#define NVOCAB 151936
#define NB 2
#define NPAST 1024
#define NPTOT 1025
#define EPSF 1e-6f
#define QKSCALE 0.08838834764831845f
#define LOGTHETA 13.815510557964274f

#define SQKV 16
#define SCH 32

// ws offsets (floats)
#define OFF_N1   0        // [NB][1024] rmsnorm(h)*ln1  (input to QKV)
#define OFF_H    2048     // [NB][1024] residual base h
#define OFF_H1   4096     // [NB][1024] h after attn residual
#define OFF_N2   6144     // [NB][1024] rmsnorm(h1)*ln2
#define OFF_QF   8192     // [NB][16][128] roped q
#define OFF_KF   12288    // [NB][8][128] roped k (new token)
#define OFF_VF   14336    // [NB][8][128] v (new token)
#define OFF_X    16384    // [NB][2048] attention output (combined, /L)
#define OFF_ACT  20480    // [NB][3072] swiglu activation
#define OFF_CNT  26624    // 256 ints (arrival counters)
#define OFF_QKV  27648    // [16][NB][4096] qkv partials
#define OFF_AM   158720   // [NB*8*2][32] chunk max
#define OFF_AL   159744   // [NB*8*2][32] chunk sumexp
#define OFF_AO   160768   // [NB*8*2][32][128] chunk weighted-V
#define OFF_WO   291840   // [16][NB][1024] Wo partials
#define OFF_G    324608   // [8][NB][3072]
#define OFF_U    373760   // [8][NB][3072]
#define OFF_WD   422912   // [16][NB][1024]

#define PK_OFF ((size_t)NB*NVOCAB)
#define PV_OFF (PK_OFF + (size_t)NL*NB*NHKV*NPTOT*HDIM)

__device__ __forceinline__ int arrive(int* cnt, int id, int* s_arr, int tid) {
  __syncthreads();
  __threadfence();
  if (tid == 0) *s_arr = atomicAdd(cnt + id, 1);
  __syncthreads();
  return *s_arr;
}
__device__ __forceinline__ void spin_all(int* cnt, int id, int nblk, int tid) {
  if (tid == 0) { while (atomicAdd(cnt + id, 0) < nblk) {} }
  __syncthreads();
  __threadfence();
}

// ---------------- K0: n1 = rmsnorm(embeds)*ln1[0]; h = embeds -----------------
__global__ __launch_bounds__(256) void k0_init(const float* __restrict__ embeds,
    const float* __restrict__ ln1, float* __restrict__ ws)
{
  int tid = threadIdx.x;
  __shared__ float red[512];
  int d = tid*4;
  float4 v0 = *(const float4*)(embeds + d);
  float4 v1 = *(const float4*)(embeds + DIM + d);
  *(float4*)(ws + OFF_H + d) = v0;
  *(float4*)(ws + OFF_H + DIM + d) = v1;
  red[tid]     = v0.x*v0.x + v0.y*v0.y + v0.z*v0.z + v0.w*v0.w;
  red[256+tid] = v1.x*v1.x + v1.y*v1.y + v1.z*v1.z + v1.w*v1.w;
  __syncthreads();
  for (int off = 128; off > 0; off >>= 1) {
    if (tid < off) { red[tid] += red[tid+off]; red[256+tid] += red[256+tid+off]; }
    __syncthreads();
  }
  float r0 = rsqrtf(red[0]/DIM + EPSF);
  float r1 = rsqrtf(red[256]/DIM + EPSF);
  float4 w = *(const float4*)(ln1 + d);
  float4 n0 = make_float4(v0.x*r0*w.x, v0.y*r0*w.y, v0.z*r0*w.z, v0.w*r0*w.w);
  float4 n1 = make_float4(v1.x*r1*w.x, v1.y*r1*w.y, v1.z*r1*w.z, v1.w*r1*w.w);
  *(float4*)(ws + OFF_N1 + d) = n0;
  *(float4*)(ws + OFF_N1 + DIM + d) = n1;
}

// ---------------- K1: QKV GEMV (split-d=16) + finalize q/k/v (qknorm+rope) ----
// grid (16,16), 256 threads
__global__ __launch_bounds__(256) void k1_qkv(
    const float* __restrict__ Wq_, const float* __restrict__ Wk_,
    const float* __restrict__ Wv_, const float* __restrict__ qnw,
    const float* __restrict__ knw, const int* __restrict__ posids,
    float* __restrict__ ws, int l)
{
  int bx = blockIdx.x, by = blockIdx.y;
  int tid = threadIdx.x;
  int* cnt = (int*)(ws + OFF_CNT);
  __shared__ __align__(16) float sh[2][64];
  __shared__ __align__(16) float red[256*9];
  __shared__ float fv[128];
  __shared__ int s_arr;
  if (tid < 128) {
    int b = tid >> 6, r = tid & 63;
    sh[b][r] = ws[OFF_N1 + b*DIM + by*64 + r];
  }
  __syncthreads();
  int ct = tid & 63, ds = tid >> 6;
  int colg = bx*256 + ct*4;
  const float* W; int O, wcol;
  if (colg < 2048)      { W = Wq_; O = 2048; wcol = colg; }
  else if (colg < 3072) { W = Wk_; O = 1024; wcol = colg - 2048; }
  else                  { W = Wv_; O = 1024; wcol = colg - 3072; }
  int rl = ds*16;
  const float* Wp = W + (size_t)l*DIM*O + (size_t)(by*64 + rl)*O + wcol;
  float a[2][4] = {};
  #pragma unroll
  for (int i = 0; i < 16; i++) {
    float4 w4 = *(const float4*)(Wp + (size_t)i*O);
    float x0 = sh[0][rl+i], x1 = sh[1][rl+i];
    a[0][0] += x0*w4.x; a[0][1] += x0*w4.y; a[0][2] += x0*w4.z; a[0][3] += x0*w4.w;
    a[1][0] += x1*w4.x; a[1][1] += x1*w4.y; a[1][2] += x1*w4.z; a[1][3] += x1*w4.w;
  }
  float* rp = red + tid*9;
  #pragma unroll
  for (int e = 0; e < 4; e++) { rp[e] = a[0][e]; rp[4+e] = a[1][e]; }
  __syncthreads();
  if (tid < 64) {
    float o[8] = {};
    #pragma unroll
    for (int j = 0; j < 4; j++) {
      const float* q = red + (size_t)(j*64 + tid)*9;
      #pragma unroll
      for (int e = 0; e < 8; e++) o[e] += q[e];
    }
    int cg = bx*256 + tid*4;
    #pragma unroll
    for (int e = 0; e < 4; e++) {
      ws[OFF_QKV + (by*NB + 0)*4096 + cg + e] = o[e];
      ws[OFF_QKV + (by*NB + 1)*4096 + cg + e] = o[4+e];
    }
  }
  // ---- finalize: last 64 arrivers each own (task t 0..31, batch b) ----
  int arr = arrive(cnt, l*8+0, &s_arr, tid);
  if (arr < 256 - 64) return;
  spin_all(cnt, l*8+0, 256, tid);
  int fin = arr - (256 - 64);
  int b = fin & 1, t = fin >> 1;
  int slot = (t < 16) ? t*128 : (t < 24) ? 2048 + (t-16)*128 : 3072 + (t-24)*128;
  float v = 0.f;
  if (tid < 128) {
    #pragma unroll
    for (int s = 0; s < SQKV; s++) v += ws[OFF_QKV + (s*NB + b)*4096 + slot + tid];
  }
  if (t >= 24) {                       // v head: no norm/rope
    if (tid < 128) ws[OFF_VF + (b*8 + (t-24))*128 + tid] = v;
    return;
  }
  red[tid] = (tid < 128) ? v*v : 0.f;
  __syncthreads();
  for (int off = 64; off > 0; off >>= 1) {
    if (tid < off) red[tid] += red[tid+off];
    __syncthreads();
  }
  float rsq = rsqrtf(red[0]/HDIM + EPSF);
  const float* nw = (t < 16) ? (qnw + l*HDIM) : (knw + l*HDIM);
  float nv = 0.f;
  if (tid < 128) { nv = v*rsq*nw[tid]; fv[tid] = nv; }
  __syncthreads();
  if (tid < 128) {
    float pos = (float)posids[b];
    int j = tid & 63;
    float ang = pos * expf(-(2.0f*(float)j/(float)HDIM)*LOGTHETA);
    float sn, cs; sincosf(ang, &sn, &cs);
    float rot = (tid < 64) ? -fv[tid+64] : fv[tid-64];
    float op = nv*cs + rot*sn;
    if (t < 16) ws[OFF_QF + (b*16 + t)*128 + tid] = op;
    else        ws[OFF_KF + (b*8 + (t-16))*128 + tid] = op;
  }
}

// ---------------- K2: KV append + chunk attention + finalize combine ----------
// grid (32, NHKV, NB), 256 threads
__global__ __launch_bounds__(256) void k2_attn(
    const float* __restrict__ pastK, const float* __restrict__ pastV,
    float* __restrict__ out, float* __restrict__ ws, int l)
{
  int c = blockIdx.x, kv = blockIdx.y, b = blockIdx.z;
  int tid = threadIdx.x;
  int* cnt = (int*)(ws + OFF_CNT);
  __shared__ __align__(16) float sq[NG][HDIM];
  __shared__ __align__(16) float sk[HDIM];
  __shared__ __align__(16) float sv[HDIM];
  __shared__ __align__(16) float po[8][NG][HDIM];
  __shared__ float pm[8][NG], pl[8][NG];
  __shared__ float fm[32], fl[32], wfc[32];
  __shared__ int s_arr;
  {
    int g = tid >> 7, o = tid & 127;
    sq[g][o] = ws[OFF_QF + (b*16 + kv*NG + g)*128 + o];
    if (tid < 128) sk[tid] = ws[OFF_KF + (b*8 + kv)*128 + tid];
    else           sv[tid-128] = ws[OFF_VF + (b*8 + kv)*128 + (tid-128)];
  }
  __syncthreads();
  int lane = tid & 63, w = tid >> 6;
  int h = (lane >> 5) & 1, q = lane & 31;
  int grp = w*2 + h;
  int p0 = c*32;
  int p1 = (c == SCH-1) ? NPTOT : p0 + 32;
  size_t pastbase = ((((size_t)l*NB + b)*NHKV + kv)*NPAST)*HDIM;
  size_t presbase = ((((size_t)l*NB + b)*NHKV + kv)*NPTOT)*HDIM;
  float4 q0 = *(const float4*)&sq[0][q*4];
  float4 q1 = *(const float4*)&sq[1][q*4];
  float sc0[5], sc1[5];
  float4 vv[5];
  int ns = 0;
  for (int p = p0 + grp; p < p1; p += 8) {
    float4 k4, v4;
    if (p < NPAST) {
      k4 = *(const float4*)(pastK + pastbase + (size_t)p*HDIM + q*4);
      v4 = *(const float4*)(pastV + pastbase + (size_t)p*HDIM + q*4);
    } else {
      k4 = *(const float4*)&sk[q*4];
      v4 = *(const float4*)&sv[q*4];
    }
    *(float4*)(out + PK_OFF + presbase + (size_t)p*HDIM + q*4) = k4;
    *(float4*)(out + PV_OFF + presbase + (size_t)p*HDIM + q*4) = v4;
    float d0 = q0.x*k4.x + q0.y*k4.y + q0.z*k4.z + q0.w*k4.w;
    float d1 = q1.x*k4.x + q1.y*k4.y + q1.z*k4.z + q1.w*k4.w;
    #pragma unroll
    for (int off = 16; off > 0; off >>= 1) {
      d0 += __shfl_xor(d0, off);
      d1 += __shfl_xor(d1, off);
    }
    sc0[ns] = d0*QKSCALE; sc1[ns] = d1*QKSCALE; vv[ns] = v4; ns++;
  }
  float m0 = -1e30f, m1 = -1e30f;
  for (int i = 0; i < ns; i++) { m0 = fmaxf(m0, sc0[i]); m1 = fmaxf(m1, sc1[i]); }
  if (q == 0) { pm[grp][0] = m0; pm[grp][1] = m1; }
  __syncthreads();
  float M0 = -1e30f, M1 = -1e30f;
  #pragma unroll
  for (int i = 0; i < 8; i++) { M0 = fmaxf(M0, pm[i][0]); M1 = fmaxf(M1, pm[i][1]); }
  float l0 = 0.f, l1 = 0.f;
  float4 o0 = {0,0,0,0}, o1 = {0,0,0,0};
  for (int i = 0; i < ns; i++) {
    float w0 = __expf(sc0[i] - M0), w1 = __expf(sc1[i] - M1);
    l0 += w0; l1 += w1;
    o0.x += w0*vv[i].x; o0.y += w0*vv[i].y; o0.z += w0*vv[i].z; o0.w += w0*vv[i].w;
    o1.x += w1*vv[i].x; o1.y += w1*vv[i].y; o1.z += w1*vv[i].z; o1.w += w1*vv[i].w;
  }
  if (q == 0) { pl[grp][0] = l0; pl[grp][1] = l1; }
  *(float4*)&po[grp][0][q*4] = o0;
  *(float4*)&po[grp][1][q*4] = o1;
  __syncthreads();
  {
    int head = tid >> 7, dd = tid & 127;
    float acc = 0.f;
    #pragma unroll
    for (int i = 0; i < 8; i++) acc += po[i][head][dd];
    int base = ((b*NHKV + kv)*NG + head)*SCH + c;
    ws[OFF_AO + (size_t)base*HDIM + dd] = acc;
    if (dd == 0) {
      float ll = 0.f;
      #pragma unroll
      for (int i = 0; i < 8; i++) ll += pl[i][head];
      ws[OFF_AM + base] = (head ? M1 : M0);
      ws[OFF_AL + base] = ll;
    }
  }
  // ---- finalize: last 32 arrivers each combine one (b,kv,g) over 32 chunks ----
  int arr = arrive(cnt, l*8+1, &s_arr, tid);
  if (arr < 512 - 32) return;
  spin_all(cnt, l*8+1, 512, tid);
  int fin = arr - (512 - 32);
  int b2 = fin >> 4, r = fin & 15, kv2 = r >> 1, g2 = r & 1;
  int hb = (b2*NHKV + kv2)*NG + g2;
  if (tid < 32) { fm[tid] = ws[OFF_AM + hb*SCH + tid]; fl[tid] = ws[OFF_AL + hb*SCH + tid]; }
  __syncthreads();
  float M = -1e30f;
  #pragma unroll
  for (int i = 0; i < 32; i++) M = fmaxf(M, fm[i]);
  if (tid < 32) wfc[tid] = __expf(fm[tid] - M);
  __syncthreads();
  float L = 0.f;
  #pragma unroll
  for (int i = 0; i < 32; i++) L += fl[i]*wfc[i];
  float invL = 1.0f/L;
  if (tid < 128) {
    float acc = 0.f;
    #pragma unroll
    for (int i = 0; i < 32; i++) acc += ws[OFF_AO + (size_t)(hb*SCH + i)*HDIM + tid]*wfc[i];
    ws[OFF_X + b2*2048 + (kv2*NG + g2)*128 + tid] = acc*invL;
  }
}

// ---------------- K3: Wo GEMV (split-head=16) + finalize h1,n2 ----------------
// grid (16,16), 256 threads
__global__ __launch_bounds__(256) void k3_wo(const float* __restrict__ Wo_,
    const float* __restrict__ ln2, float* __restrict__ ws, int l)
{
  int bx = blockIdx.x, head = blockIdx.y;
  int tid = threadIdx.x;
  int* cnt = (int*)(ws + OFF_CNT);
  __shared__ __align__(16) float xs[NB][HDIM];
  __shared__ __align__(16) float red[256*9];
  __shared__ int s_arr;
  {
    int b = tid >> 7, dd = tid & 127;
    xs[b][dd] = ws[OFF_X + b*2048 + head*128 + dd];
  }
  __syncthreads();
  int ct = tid & 15, ds = tid >> 4;
  int col = bx*64 + ct*4;
  int r0 = ds*8;
  const float* Wp = Wo_ + (size_t)l*(NHQ*HDIM)*DIM + (size_t)(head*HDIM + r0)*DIM + col;
  float a[2][4] = {};
  #pragma unroll
  for (int i = 0; i < 8; i++) {
    float4 w4 = *(const float4*)(Wp + (size_t)i*DIM);
    float x0 = xs[0][r0+i], x1 = xs[1][r0+i];
    a[0][0] += x0*w4.x; a[0][1] += x0*w4.y; a[0][2] += x0*w4.z; a[0][3] += x0*w4.w;
    a[1][0] += x1*w4.x; a[1][1] += x1*w4.y; a[1][2] += x1*w4.z; a[1][3] += x1*w4.w;
  }
  float* rp = red + tid*9;
  #pragma unroll
  for (int e = 0; e < 4; e++) { rp[e] = a[0][e]; rp[4+e] = a[1][e]; }
  __syncthreads();
  if (tid < 16) {
    float o[8] = {};
    #pragma unroll
    for (int jj = 0; jj < 16; jj++) {
      const float* qq = red + (size_t)(jj*16 + tid)*9;
      #pragma unroll
      for (int e = 0; e < 8; e++) o[e] += qq[e];
    }
    int cg = bx*64 + tid*4;
    #pragma unroll
    for (int e = 0; e < 4; e++) {
      ws[OFF_WO + (head*NB + 0)*DIM + cg + e] = o[e];
      ws[OFF_WO + (head*NB + 1)*DIM + cg + e] = o[4+e];
    }
  }
  // ---- finalize: last 2 arrivers (per batch): h1 = h + sum, n2 = norm*ln2 ----
  int arr = arrive(cnt, l*8+2, &s_arr, tid);
  if (arr < 256 - 2) return;
  spin_all(cnt, l*8+2, 256, tid);
  int b = arr - (256 - 2);
  int d = tid*4;
  float4 acc = *(const float4*)(ws + OFF_H + b*DIM + d);
  #pragma unroll
  for (int s = 0; s < 16; s++) {
    float4 p = *(const float4*)(ws + OFF_WO + (s*NB + b)*DIM + d);
    acc.x += p.x; acc.y += p.y; acc.z += p.z; acc.w += p.w;
  }
  *(float4*)(ws + OFF_H1 + b*DIM + d) = acc;
  red[tid] = acc.x*acc.x + acc.y*acc.y + acc.z*acc.z + acc.w*acc.w;
  __syncthreads();
  for (int off = 128; off > 0; off >>= 1) {
    if (tid < off) red[tid] += red[tid+off];
    __syncthreads();
  }
  float rsq = rsqrtf(red[0]/DIM + EPSF);
  float4 lw = *(const float4*)(ln2 + l*DIM + d);
  float4 n2 = make_float4(acc.x*rsq*lw.x, acc.y*rsq*lw.y, acc.z*rsq*lw.z, acc.w*rsq*lw.w);
  *(float4*)(ws + OFF_N2 + b*DIM + d) = n2;
}

// ---------------- K4: Wg/Wu GEMV (split-d=8) + finalize swiglu act ------------
// grid (48,8), 256 threads
__global__ __launch_bounds__(256) void k4_mlp1(const float* __restrict__ Wg_,
    const float* __restrict__ Wu_, float* __restrict__ ws, int l)
{
  int bx = blockIdx.x, by = blockIdx.y;
  int tid = threadIdx.x;
  int* cnt = (int*)(ws + OFF_CNT);
  __shared__ __align__(16) float sh[2][128];
  __shared__ __align__(16) float red[256*9];
  __shared__ int s_arr;
  {
    int b = tid >> 7, r = tid & 127;
    sh[b][r] = ws[OFF_N2 + b*DIM + by*128 + r];
  }
  __syncthreads();
  int ct = tid & 15, ds = tid >> 4;
  int col = bx*64 + ct*4;
  int rl = ds*8;
  const float* Wgp = Wg_ + (size_t)l*DIM*NFF + (size_t)(by*128 + rl)*NFF + col;
  const float* Wup = Wu_ + (size_t)l*DIM*NFF + (size_t)(by*128 + rl)*NFF + col;
  float ag[2][4] = {}, au[2][4] = {};
  #pragma unroll
  for (int i = 0; i < 8; i++) {
    float4 wg = *(const float4*)(Wgp + (size_t)i*NFF);
    float4 wu = *(const float4*)(Wup + (size_t)i*NFF);
    float x0 = sh[0][rl+i], x1 = sh[1][rl+i];
    ag[0][0] += x0*wg.x; ag[0][1] += x0*wg.y; ag[0][2] += x0*wg.z; ag[0][3] += x0*wg.w;
    ag[1][0] += x1*wg.x; ag[1][1] += x1*wg.y; ag[1][2] += x1*wg.z; ag[1][3] += x1*wg.w;
    au[0][0] += x0*wu.x; au[0][1] += x0*wu.y; au[0][2] += x0*wu.z; au[0][3] += x0*wu.w;
    au[1][0] += x1*wu.x; au[1][1] += x1*wu.y; au[1][2] += x1*wu.z; au[1][3] += x1*wu.w;
  }
  float* rp = red + tid*9;
  #pragma unroll
  for (int e = 0; e < 4; e++) { rp[e] = ag[0][e]; rp[4+e] = ag[1][e]; }
  __syncthreads();
  if (tid < 16) {
    float o[8] = {};
    #pragma unroll
    for (int jj = 0; jj < 16; jj++) {
      const float* qq = red + (size_t)(jj*16 + tid)*9;
      #pragma unroll
      for (int e = 0; e < 8; e++) o[e] += qq[e];
    }
    int cg = bx*64 + tid*4;
    #pragma unroll
    for (int e = 0; e < 4; e++) {
      ws[OFF_G + (by*NB + 0)*NFF + cg + e] = o[e];
      ws[OFF_G + (by*NB + 1)*NFF + cg + e] = o[4+e];
    }
  }
  __syncthreads();
  #pragma unroll
  for (int e = 0; e < 4; e++) { rp[e] = au[0][e]; rp[4+e] = au[1][e]; }
  __syncthreads();
  if (tid < 16) {
    float o[8] = {};
    #pragma unroll
    for (int jj = 0; jj < 16; jj++) {
      const float* qq = red + (size_t)(jj*16 + tid)*9;
      #pragma unroll
      for (int e = 0; e < 8; e++) o[e] += qq[e];
    }
    int cg = bx*64 + tid*4;
    #pragma unroll
    for (int e = 0; e < 4; e++) {
      ws[OFF_U + (by*NB + 0)*NFF + cg + e] = o[e];
      ws[OFF_U + (by*NB + 1)*NFF + cg + e] = o[4+e];
    }
  }
  // ---- finalize: last 12 arrivers: act = silu(g)*u for 256 ff cols × 2 b ----
  int arr = arrive(cnt, l*8+3, &s_arr, tid);
  if (arr < 384 - 12) return;
  spin_all(cnt, l*8+3, 384, tid);
  int fin = arr - (384 - 12);
  int ff0 = fin*256;
  #pragma unroll
  for (int t = 0; t < 2; t++) {
    int e = tid + t*256;
    int b = e >> 8, ffl = e & 255;
    int ff = ff0 + ffl;
    float g = 0.f, u = 0.f;
    #pragma unroll
    for (int s = 0; s < 8; s++) {
      g += ws[OFF_G + (s*NB + b)*NFF + ff];
      u += ws[OFF_U + (s*NB + b)*NFF + ff];
    }
    ws[OFF_ACT + b*NFF + ff] = (g / (1.0f + __expf(-g)))*u;
  }
}

// ---------------- K5: Wd GEMV (split-ff=16) + finalize h2, n1(next) -----------
// grid (16,16), 256 threads
__global__ __launch_bounds__(256) void k5_mlp2(const float* __restrict__ Wd_,
    const float* __restrict__ ln1, float* __restrict__ ws, int l)
{
  int bx = blockIdx.x, by = blockIdx.y;
  int tid = threadIdx.x;
  int* cnt = (int*)(ws + OFF_CNT);
  __shared__ __align__(16) float act[2][192];
  __shared__ __align__(16) float red[256*9];
  __shared__ int s_arr;
  for (int e = tid; e < 384; e += 256) {
    int b = (e >= 192);
    int loc = e - b*192;
    act[b][loc] = ws[OFF_ACT + b*NFF + by*192 + loc];
  }
  __syncthreads();
  int ct = tid & 15, ds = tid >> 4;
  int col = bx*64 + ct*4;
  int loc0 = ds*12;
  const float* Wp = Wd_ + (size_t)l*NFF*DIM + (size_t)(by*192 + loc0)*DIM + col;
  float a[2][4] = {};
  #pragma unroll
  for (int i = 0; i < 12; i++) {
    float4 w4 = *(const float4*)(Wp + (size_t)i*DIM);
    float x0 = act[0][loc0+i], x1 = act[1][loc0+i];
    a[0][0] += x0*w4.x; a[0][1] += x0*w4.y; a[0][2] += x0*w4.z; a[0][3] += x0*w4.w;
    a[1][0] += x1*w4.x; a[1][1] += x1*w4.y; a[1][2] += x1*w4.z; a[1][3] += x1*w4.w;
  }
  float* rp = red + tid*9;
  #pragma unroll
  for (int e = 0; e < 4; e++) { rp[e] = a[0][e]; rp[4+e] = a[1][e]; }
  __syncthreads();
  if (tid < 16) {
    float o[8] = {};
    #pragma unroll
    for (int jj = 0; jj < 16; jj++) {
      const float* qq = red + (size_t)(jj*16 + tid)*9;
      #pragma unroll
      for (int e = 0; e < 8; e++) o[e] += qq[e];
    }
    int cg = bx*64 + tid*4;
    #pragma unroll
    for (int e = 0; e < 4; e++) {
      ws[OFF_WD + (by*NB + 0)*DIM + cg + e] = o[e];
      ws[OFF_WD + (by*NB + 1)*DIM + cg + e] = o[4+e];
    }
  }
  // ---- finalize: last 2 arrivers: h2 = h1 + sum; n1 = norm(h2)*ln1[l+1] ----
  int arr = arrive(cnt, l*8+4, &s_arr, tid);
  if (arr < 256 - 2) return;
  spin_all(cnt, l*8+4, 256, tid);
  int b = arr - (256 - 2);
  int d = tid*4;
  float4 acc = *(const float4*)(ws + OFF_H1 + b*DIM + d);
  #pragma unroll
  for (int s = 0; s < 16; s++) {
    float4 p = *(const float4*)(ws + OFF_WD + (s*NB + b)*DIM + d);
    acc.x += p.x; acc.y += p.y; acc.z += p.z; acc.w += p.w;
  }
  *(float4*)(ws + OFF_H + b*DIM + d) = acc;
  red[tid] = acc.x*acc.x + acc.y*acc.y + acc.z*acc.z + acc.w*acc.w;
  __syncthreads();
  for (int off = 128; off > 0; off >>= 1) {
    if (tid < off) red[tid] += red[tid+off];
    __syncthreads();
  }
  if (l < NL-1) {
    float rsq = rsqrtf(red[0]/DIM + EPSF);
    float4 lw = *(const float4*)(ln1 + (l+1)*DIM + d);
    float4 n1 = make_float4(acc.x*rsq*lw.x, acc.y*rsq*lw.y, acc.z*rsq*lw.z, acc.w*rsq*lw.w);
    *(float4*)(ws + OFF_N1 + b*DIM + d) = n1;
  }
}

// ---------------- K6: final rmsnorm + lm_head GEMV ----------------------------
__global__ __launch_bounds__(256) void k6_lmhead(const float* __restrict__ lmw,
    const float* __restrict__ fnw, const float* __restrict__ ws,
    float* __restrict__ out)
{
  __shared__ __align__(16) float nf[NB*DIM];
  __shared__ __align__(16) float red[256*9];
  int tid = threadIdx.x;
  float s0 = 0.f, sB = 0.f;
  float hv[8];
  for (int k = 0; k < 8; k++) {
    int idx = tid + k*256;
    int b = idx >> 10;
    float v = ws[OFF_H + idx];
    hv[k] = v;
    if (b == 0) s0 += v*v; else sB += v*v;
  }
  red[tid] = s0; red[256+tid] = sB;
  __syncthreads();
  for (int off = 128; off > 0; off >>= 1) {
    if (tid < off) { red[tid] += red[tid+off]; red[256+tid] += red[256+tid+off]; }
    __syncthreads();
  }
  float r0n = rsqrtf(red[0]/DIM + EPSF);
  float r1n = rsqrtf(red[256]/DIM + EPSF);
  __syncthreads();
  for (int k = 0; k < 8; k++) {
    int idx = tid + k*256;
    int b = idx >> 10, d = idx & 1023;
    nf[idx] = hv[k] * (b ? r1n : r0n) * fnw[d];
  }
  __syncthreads();
  int ct = tid & 63, ds = tid >> 6;
  int quad = blockIdx.x*64 + ct;
  int valid = quad < (NVOCAB/4);
  int col = quad*4;
  float a[2][4] = {};
  if (valid) {
    const float* Wp = lmw + (size_t)(ds*256)*NVOCAB + col;
    for (int i = 0; i < 256; i++) {
      float4 w4 = *(const float4*)(Wp + (size_t)i*NVOCAB);
      float x0 = nf[ds*256+i], x1 = nf[DIM+ds*256+i];
      a[0][0] += x0*w4.x; a[0][1] += x0*w4.y; a[0][2] += x0*w4.z; a[0][3] += x0*w4.w;
      a[1][0] += x1*w4.x; a[1][1] += x1*w4.y; a[1][2] += x1*w4.z; a[1][3] += x1*w4.w;
    }
  }
  float* rp = red + tid*9;
  #pragma unroll
  for (int e = 0; e < 4; e++) { rp[e] = a[0][e]; rp[4+e] = a[1][e]; }
  __syncthreads();
  if (tid < 64 && valid) {
    float o[8] = {};
    #pragma unroll
    for (int jj = 0; jj < 4; jj++) {
      const float* qq = red + (size_t)(jj*64 + tid)*9;
      #pragma unroll
      for (int e = 0; e < 8; e++) o[e] += qq[e];
    }
    #pragma unroll
    for (int e = 0; e < 4; e++) {
      out[col + e] = o[e];
      out[NVOCAB + col + e] = o[4+e];
    }
  }
}

extern "C" void kernel_launch(void* const* d_in, const int* in_sizes, int n_in,
                              void* d_out, int out_size, void* d_ws, size_t ws_size,
                              hipStream_t stream) {
  (void)in_sizes; (void)n_in; (void)out_size; (void)ws_size;
  const float* embeds = (const float*)d_in[0];
  const int*   posids = (const int*)d_in[1];
  const float* pastK  = (const float*)d_in[2];
  const float* pastV  = (const float*)d_in[3];
  const float* Wq     = (const float*)d_in[4];
  const float* Wk     = (const float*)d_in[5];
  const float* Wv     = (const float*)d_in[6];
  const float* Wo     = (const float*)d_in[7];
  const float* Wg     = (const float*)d_in[8];
  const float* Wu     = (const float*)d_in[9];
  const float* Wd     = (const float*)d_in[10];
  const float* ln1    = (const float*)d_in[11];
  const float* ln2    = (const float*)d_in[12];
  const float* qnw    = (const float*)d_in[13];
  const float* knw    = (const float*)d_in[14];
  const float* fnw    = (const float*)d_in[15];
  const float* lmw    = (const float*)d_in[16];
  float* out = (float*)d_out;
  float* ws  = (float*)d_ws;

  hipMemsetAsync((char*)d_ws + (size_t)OFF_CNT*sizeof(float), 0, 256*sizeof(int), stream);
  k0_init<<<1, 256, 0, stream>>>(embeds, ln1, ws);
  for (int l = 0; l < NL; l++) {
    k1_qkv <<<dim3(16, 16), 256, 0, stream>>>(Wq, Wk, Wv, qnw, knw, posids, ws, l);
    k2_attn<<<dim3(SCH, NHKV, NB), 256, 0, stream>>>(pastK, pastV, out, ws, l);
    k3_wo  <<<dim3(16, 16), 256, 0, stream>>>(Wo, ln2, ws, l);
    k4_mlp1<<<dim3(48, 8), 256, 0, stream>>>(Wg, Wu, ws, l);
    k5_mlp2<<<dim3(16, 16), 256, 0, stream>>>(Wd, ln1, ws, l);
  }
  k6_lmhead<<<(NVOCAB/4 + 63)/64, 256, 0, stream>>>(lmw, fnw, ws, out);
}

// Round 4
// 1470.333 us; speedup vs baseline: 3.8037x; 3.8037x over previous
//
#include <hip/hip_runtime.h>
#include <math.h>

#define NL 28
#define DIM 1024
#define NHQ 16
#define NHKV 8
#define HDIM 128
#define NG 2
#define NFF 3072
#define NVOCAB 151936
#define NB 2
#define NPAST 1024
#define NPTOT 1025
#define EPSF 1e-6f
#define QKSCALE 0.08838834764831845f
#define LOGTHETA 13.815510557964274f

#define SQKV 8
#define SCH 32

// ws offsets (floats)
#define OFF_N1   0        // [NB][1024] rmsnorm(embeds)*ln1[0] (layer-0 only)
#define OFF_H    2048     // [NB][1024] residual h entering current layer
#define OFF_H1   4096     // [NB][1024] h after attn residual
#define OFF_QKV  8192     // [8][NB][4096] qkv partials
#define OFF_AM   73728    // [NB*16][32] chunk max
#define OFF_AL   74752    // [NB*16][32] chunk sumexp
#define OFF_AO   75776    // [NB*16][32][128] chunk weighted-V
#define OFF_WO   206848   // [8][NB][1024] Wo partials
#define OFF_G    223232   // [8][NB][3072]
#define OFF_U    272384   // [8][NB][3072]
#define OFF_WD   321536   // [8][NB][1024]

#define PK_OFF ((size_t)NB*NVOCAB)
#define PV_OFF (PK_OFF + (size_t)NL*NB*NHKV*NPTOT*HDIM)

// ---------------- K0: n1 = rmsnorm(embeds)*ln1[0]; h = embeds -----------------
__global__ __launch_bounds__(256) void k0_init(const float* __restrict__ embeds,
    const float* __restrict__ ln1, float* __restrict__ ws)
{
  int tid = threadIdx.x;
  __shared__ float red[512];
  int d = tid*4;
  float4 v0 = *(const float4*)(embeds + d);
  float4 v1 = *(const float4*)(embeds + DIM + d);
  *(float4*)(ws + OFF_H + d) = v0;
  *(float4*)(ws + OFF_H + DIM + d) = v1;
  red[tid]     = v0.x*v0.x + v0.y*v0.y + v0.z*v0.z + v0.w*v0.w;
  red[256+tid] = v1.x*v1.x + v1.y*v1.y + v1.z*v1.z + v1.w*v1.w;
  __syncthreads();
  for (int off = 128; off > 0; off >>= 1) {
    if (tid < off) { red[tid] += red[tid+off]; red[256+tid] += red[256+tid+off]; }
    __syncthreads();
  }
  float r0 = rsqrtf(red[0]/DIM + EPSF);
  float r1 = rsqrtf(red[256]/DIM + EPSF);
  float4 w = *(const float4*)(ln1 + d);
  float4 n0 = make_float4(v0.x*r0*w.x, v0.y*r0*w.y, v0.z*r0*w.z, v0.w*r0*w.w);
  float4 n1 = make_float4(v1.x*r1*w.x, v1.y*r1*w.y, v1.z*r1*w.z, v1.w*r1*w.w);
  *(float4*)(ws + OFF_N1 + d) = n0;
  *(float4*)(ws + OFF_N1 + DIM + d) = n1;
}

// ---------------- K1: [l>0: h2/n1 recompute] + QKV GEMV partials --------------
// grid (64 colTiles(64), 8 rowSplits(128)), 256 threads
__global__ __launch_bounds__(256) void k1_qkv(
    const float* __restrict__ Wq_, const float* __restrict__ Wk_,
    const float* __restrict__ Wv_, const float* __restrict__ ln1,
    float* __restrict__ ws, int l)
{
  int bx = blockIdx.x, by = blockIdx.y;
  int tid = threadIdx.x;
  __shared__ __align__(16) float sh[NB][128];
  __shared__ __align__(16) float red[256*9];

  // -- issue weight loads first (independent of preamble) --
  int ct = tid & 15, rs = tid >> 4;
  int colg = bx*64 + ct*4;
  const float* W; int O; int wcol;
  if (bx < 32)      { W = Wq_; O = 2048; wcol = colg; }
  else if (bx < 48) { W = Wk_; O = 1024; wcol = colg - 2048; }
  else              { W = Wv_; O = 1024; wcol = colg - 3072; }
  int r0 = rs*8;
  const float* Wp = W + (size_t)l*DIM*O + (size_t)(by*128 + r0)*O + wcol;
  float4 wb[8];
  #pragma unroll
  for (int i = 0; i < 8; i++) wb[i] = *(const float4*)(Wp + (size_t)i*O);

  // -- preamble: produce sh = n1 slice [2][128] --
  if (l == 0) {
    int b = tid >> 7, r = tid & 127;
    sh[b][r] = ws[OFF_N1 + b*DIM + by*128 + r];
    __syncthreads();
  } else {
    int d = tid*4;
    float4 a0 = *(const float4*)(ws + OFF_H1 + d);
    float4 a1 = *(const float4*)(ws + OFF_H1 + DIM + d);
    #pragma unroll
    for (int s = 0; s < 8; s++) {
      float4 p0 = *(const float4*)(ws + OFF_WD + (s*NB + 0)*DIM + d);
      float4 p1 = *(const float4*)(ws + OFF_WD + (s*NB + 1)*DIM + d);
      a0.x += p0.x; a0.y += p0.y; a0.z += p0.z; a0.w += p0.w;
      a1.x += p1.x; a1.y += p1.y; a1.z += p1.z; a1.w += p1.w;
    }
    if (bx == 0 && by == 0) {      // materialize h (residual base for k4)
      *(float4*)(ws + OFF_H + d) = a0;
      *(float4*)(ws + OFF_H + DIM + d) = a1;
    }
    red[tid]     = a0.x*a0.x + a0.y*a0.y + a0.z*a0.z + a0.w*a0.w;
    red[256+tid] = a1.x*a1.x + a1.y*a1.y + a1.z*a1.z + a1.w*a1.w;
    __syncthreads();
    for (int off = 128; off > 0; off >>= 1) {
      if (tid < off) { red[tid] += red[tid+off]; red[256+tid] += red[256+tid+off]; }
      __syncthreads();
    }
    float rq0 = rsqrtf(red[0]/DIM + EPSF);
    float rq1 = rsqrtf(red[256]/DIM + EPSF);
    float4 lw = *(const float4*)(ln1 + (size_t)l*DIM + d);
    int r = d - by*128;
    if (r >= 0 && r < 128) {
      sh[0][r] = a0.x*rq0*lw.x; sh[0][r+1] = a0.y*rq0*lw.y;
      sh[0][r+2] = a0.z*rq0*lw.z; sh[0][r+3] = a0.w*rq0*lw.w;
      sh[1][r] = a1.x*rq1*lw.x; sh[1][r+1] = a1.y*rq1*lw.y;
      sh[1][r+2] = a1.z*rq1*lw.z; sh[1][r+3] = a1.w*rq1*lw.w;
    }
    __syncthreads();
  }

  // -- GEMV --
  float a[2][4] = {};
  #pragma unroll
  for (int i = 0; i < 8; i++) {
    float x0 = sh[0][r0+i], x1 = sh[1][r0+i];
    a[0][0] += x0*wb[i].x; a[0][1] += x0*wb[i].y; a[0][2] += x0*wb[i].z; a[0][3] += x0*wb[i].w;
    a[1][0] += x1*wb[i].x; a[1][1] += x1*wb[i].y; a[1][2] += x1*wb[i].z; a[1][3] += x1*wb[i].w;
  }
  float* rp = red + tid*9;
  #pragma unroll
  for (int e = 0; e < 4; e++) { rp[e] = a[0][e]; rp[4+e] = a[1][e]; }
  __syncthreads();
  if (tid < 16) {
    float o[8] = {};
    #pragma unroll
    for (int j = 0; j < 16; j++) {
      const float* q = red + (size_t)(j*16 + tid)*9;
      #pragma unroll
      for (int e = 0; e < 8; e++) o[e] += q[e];
    }
    int cg = bx*64 + tid*4;
    #pragma unroll
    for (int e = 0; e < 4; e++) {
      ws[OFF_QKV + (by*NB + 0)*4096 + cg + e] = o[e];
      ws[OFF_QKV + (by*NB + 1)*4096 + cg + e] = o[4+e];
    }
  }
}

// ---------------- K2: qkv finalize + qknorm + rope + KV copy + chunk attention
// grid (32 chunks, NHKV, NB), 256 threads
__global__ __launch_bounds__(256) void k2_attn(
    const float* __restrict__ pastK, const float* __restrict__ pastV,
    const int* __restrict__ posids, const float* __restrict__ qnw,
    const float* __restrict__ knw, float* __restrict__ out,
    float* __restrict__ ws, int l)
{
  int c = blockIdx.x, kv = blockIdx.y, b = blockIdx.z;
  int tid = threadIdx.x;
  __shared__ __align__(16) float qf[NG][HDIM];
  __shared__ __align__(16) float kf[HDIM];
  __shared__ __align__(16) float vf[HDIM];
  __shared__ __align__(16) float pre[3*HDIM];
  __shared__ __align__(16) float po[8][NG][HDIM];
  __shared__ float red[256];
  __shared__ float pm[8][NG], pl[8][NG];

  int g = tid >> 7, o = tid & 127;
  int hq = kv*NG + g;
  float qraw = 0.f, kvraw = 0.f;
  #pragma unroll
  for (int s = 0; s < SQKV; s++) qraw += ws[OFF_QKV + (s*NB + b)*4096 + hq*HDIM + o];
  if (g == 0) {
    #pragma unroll
    for (int s = 0; s < SQKV; s++) kvraw += ws[OFF_QKV + (s*NB + b)*4096 + 2048 + kv*HDIM + o];
  } else {
    #pragma unroll
    for (int s = 0; s < SQKV; s++) kvraw += ws[OFF_QKV + (s*NB + b)*4096 + 3072 + kv*HDIM + o];
  }
  red[tid] = qraw*qraw;
  __syncthreads();
  for (int off = 64; off > 0; off >>= 1) {
    if (o < off) red[tid] += red[tid+off];
    __syncthreads();
  }
  float qr = rsqrtf(red[g*128]/HDIM + EPSF);
  __syncthreads();
  red[tid] = (g == 0) ? kvraw*kvraw : 0.f;
  __syncthreads();
  for (int off = 128; off > 0; off >>= 1) {
    if (tid < off) red[tid] += red[tid+off];
    __syncthreads();
  }
  float kr = rsqrtf(red[0]/HDIM + EPSF);
  pre[g*HDIM + o] = qraw*qr*qnw[l*HDIM + o];
  if (g == 0) pre[2*HDIM + o] = kvraw*kr*knw[l*HDIM + o];
  else vf[o] = kvraw;
  __syncthreads();
  float pos = (float)posids[b];
  int j = o & 63;
  float ang = pos * expf(-(2.0f*(float)j/(float)HDIM)*LOGTHETA);
  float sn, cs;
  sincosf(ang, &sn, &cs);
  {
    float qv = pre[g*HDIM + o];
    float qo = (o < 64) ? -pre[g*HDIM + o + 64] : pre[g*HDIM + o - 64];
    qf[g][o] = qv*cs + qo*sn;
    if (g == 0) {
      float kx = pre[2*HDIM + o];
      float ko = (o < 64) ? -pre[2*HDIM + o + 64] : pre[2*HDIM + o - 64];
      kf[o] = kx*cs + ko*sn;
    }
  }
  __syncthreads();

  int lane = tid & 63, w = tid >> 6;
  int h = (lane >> 5) & 1, q = lane & 31;
  int grp = w*2 + h;
  int p0 = c*32;
  int p1 = (c == SCH-1) ? NPTOT : p0 + 32;
  size_t pastbase = ((((size_t)l*NB + b)*NHKV + kv)*NPAST)*HDIM;
  size_t presbase = ((((size_t)l*NB + b)*NHKV + kv)*NPTOT)*HDIM;
  float4 q0 = *(const float4*)&qf[0][q*4];
  float4 q1 = *(const float4*)&qf[1][q*4];
  float sc0[5], sc1[5];
  float4 vv[5];
  int ns = 0;
  for (int p = p0 + grp; p < p1; p += 8) {
    float4 k4, v4;
    if (p < NPAST) {
      k4 = *(const float4*)(pastK + pastbase + (size_t)p*HDIM + q*4);
      v4 = *(const float4*)(pastV + pastbase + (size_t)p*HDIM + q*4);
    } else {
      k4 = *(const float4*)&kf[q*4];
      v4 = *(const float4*)&vf[q*4];
    }
    *(float4*)(out + PK_OFF + presbase + (size_t)p*HDIM + q*4) = k4;
    *(float4*)(out + PV_OFF + presbase + (size_t)p*HDIM + q*4) = v4;
    float d0 = q0.x*k4.x + q0.y*k4.y + q0.z*k4.z + q0.w*k4.w;
    float d1 = q1.x*k4.x + q1.y*k4.y + q1.z*k4.z + q1.w*k4.w;
    #pragma unroll
    for (int off = 16; off > 0; off >>= 1) {
      d0 += __shfl_xor(d0, off);
      d1 += __shfl_xor(d1, off);
    }
    sc0[ns] = d0*QKSCALE; sc1[ns] = d1*QKSCALE; vv[ns] = v4; ns++;
  }
  float m0 = -1e30f, m1 = -1e30f;
  for (int i = 0; i < ns; i++) { m0 = fmaxf(m0, sc0[i]); m1 = fmaxf(m1, sc1[i]); }
  if (q == 0) { pm[grp][0] = m0; pm[grp][1] = m1; }
  __syncthreads();
  float M0 = -1e30f, M1 = -1e30f;
  #pragma unroll
  for (int i = 0; i < 8; i++) { M0 = fmaxf(M0, pm[i][0]); M1 = fmaxf(M1, pm[i][1]); }
  float l0 = 0.f, l1 = 0.f;
  float4 o0 = {0,0,0,0}, o1 = {0,0,0,0};
  for (int i = 0; i < ns; i++) {
    float w0 = __expf(sc0[i] - M0), w1 = __expf(sc1[i] - M1);
    l0 += w0; l1 += w1;
    o0.x += w0*vv[i].x; o0.y += w0*vv[i].y; o0.z += w0*vv[i].z; o0.w += w0*vv[i].w;
    o1.x += w1*vv[i].x; o1.y += w1*vv[i].y; o1.z += w1*vv[i].z; o1.w += w1*vv[i].w;
  }
  if (q == 0) { pl[grp][0] = l0; pl[grp][1] = l1; }
  *(float4*)&po[grp][0][q*4] = o0;
  *(float4*)&po[grp][1][q*4] = o1;
  __syncthreads();
  {
    int head = tid >> 7, dd = tid & 127;
    float acc = 0.f;
    #pragma unroll
    for (int i = 0; i < 8; i++) acc += po[i][head][dd];
    int base = ((b*NHKV + kv)*NG + head)*SCH + c;
    ws[OFF_AO + (size_t)base*HDIM + dd] = acc;
    if (dd == 0) {
      float ll = 0.f;
      #pragma unroll
      for (int i = 0; i < 8; i++) ll += pl[i][head];
      ws[OFF_AM + base] = (head ? M1 : M0);
      ws[OFF_AL + base] = ll;
    }
  }
}

// ---------------- K3: softmax combine + Wo GEMV partials ----------------------
// grid (32 colTiles(32), 8 headPairs(256 rows)), 256 threads
__global__ __launch_bounds__(256) void k3_wo(const float* __restrict__ Wo_,
    float* __restrict__ ws, int l)
{
  int bx = blockIdx.x, by = blockIdx.y;
  int tid = threadIdx.x;
  __shared__ __align__(16) float x[NB][256];
  __shared__ float wf[NB][2][SCH];
  __shared__ float invL[NB][2];
  __shared__ __align__(16) float red[256*9];

  // -- issue weight loads first --
  int ct = tid & 7, rs = tid >> 3;
  int col = bx*32 + ct*4;
  int r0 = rs*8;
  const float* Wp = Wo_ + (size_t)l*(NHQ*HDIM)*DIM + (size_t)(by*256 + r0)*DIM + col;
  float4 wb[8];
  #pragma unroll
  for (int i = 0; i < 8; i++) wb[i] = *(const float4*)(Wp + (size_t)i*DIM);

  if (tid < 4) {
    int b = tid >> 1, hh = tid & 1;
    int hb = b*16 + by*2 + hh;
    const float* mp = ws + OFF_AM + hb*SCH;
    const float* lp = ws + OFF_AL + hb*SCH;
    float M = -1e30f;
    for (int cc = 0; cc < SCH; cc++) M = fmaxf(M, mp[cc]);
    float L = 0.f;
    for (int cc = 0; cc < SCH; cc++) { float f = __expf(mp[cc]-M); wf[b][hh][cc] = f; L += lp[cc]*f; }
    invL[b][hh] = 1.0f/L;
  }
  __syncthreads();
  for (int e = tid; e < 512; e += 256) {
    int b = e >> 8, rr = e & 255, hh = rr >> 7, dd = rr & 127;
    int hb = b*16 + by*2 + hh;
    const float* op = ws + OFF_AO + (size_t)(hb*SCH)*HDIM + dd;
    float acc = 0.f;
    for (int cc = 0; cc < SCH; cc++) acc += op[(size_t)cc*HDIM]*wf[b][hh][cc];
    x[b][rr] = acc*invL[b][hh];
  }
  __syncthreads();
  float a[2][4] = {};
  #pragma unroll
  for (int i = 0; i < 8; i++) {
    float x0 = x[0][r0+i], x1 = x[1][r0+i];
    a[0][0] += x0*wb[i].x; a[0][1] += x0*wb[i].y; a[0][2] += x0*wb[i].z; a[0][3] += x0*wb[i].w;
    a[1][0] += x1*wb[i].x; a[1][1] += x1*wb[i].y; a[1][2] += x1*wb[i].z; a[1][3] += x1*wb[i].w;
  }
  float* rp = red + tid*9;
  #pragma unroll
  for (int e = 0; e < 4; e++) { rp[e] = a[0][e]; rp[4+e] = a[1][e]; }
  __syncthreads();
  if (tid < 8) {
    float o[8] = {};
    #pragma unroll
    for (int j = 0; j < 32; j++) {
      const float* qq = red + (size_t)(j*8 + tid)*9;
      #pragma unroll
      for (int e = 0; e < 8; e++) o[e] += qq[e];
    }
    int cg = bx*32 + tid*4;
    #pragma unroll
    for (int e = 0; e < 4; e++) {
      ws[OFF_WO + (by*NB + 0)*DIM + cg + e] = o[e];
      ws[OFF_WO + (by*NB + 1)*DIM + cg + e] = o[4+e];
    }
  }
}

// ---------------- K4: h1+n2 recompute + Wg/Wu GEMV partials -------------------
// grid (48 colTiles(64), 8 rowSplits(128)), 256 threads
__global__ __launch_bounds__(256) void k4_mlp1(const float* __restrict__ Wg_,
    const float* __restrict__ Wu_, const float* __restrict__ ln2,
    float* __restrict__ ws, int l)
{
  int bx = blockIdx.x, by = blockIdx.y;
  int tid = threadIdx.x;
  __shared__ __align__(16) float sh[NB][128];
  __shared__ __align__(16) float red[256*9];

  // -- issue weight loads first --
  int ct = tid & 15, rs = tid >> 4;
  int col = bx*64 + ct*4;
  int r0 = rs*8;
  const float* Wgp = Wg_ + (size_t)l*DIM*NFF + (size_t)(by*128 + r0)*NFF + col;
  const float* Wup = Wu_ + (size_t)l*DIM*NFF + (size_t)(by*128 + r0)*NFF + col;
  float4 wg[8], wu[8];
  #pragma unroll
  for (int i = 0; i < 8; i++) {
    wg[i] = *(const float4*)(Wgp + (size_t)i*NFF);
    wu[i] = *(const float4*)(Wup + (size_t)i*NFF);
  }

  // -- preamble: h1 = h + sum(WO partials); n2 slice --
  int d = tid*4;
  float4 a0 = *(const float4*)(ws + OFF_H + d);
  float4 a1 = *(const float4*)(ws + OFF_H + DIM + d);
  #pragma unroll
  for (int s = 0; s < 8; s++) {
    float4 p0 = *(const float4*)(ws + OFF_WO + (s*NB + 0)*DIM + d);
    float4 p1 = *(const float4*)(ws + OFF_WO + (s*NB + 1)*DIM + d);
    a0.x += p0.x; a0.y += p0.y; a0.z += p0.z; a0.w += p0.w;
    a1.x += p1.x; a1.y += p1.y; a1.z += p1.z; a1.w += p1.w;
  }
  if (bx == 0 && by == 0) {
    *(float4*)(ws + OFF_H1 + d) = a0;
    *(float4*)(ws + OFF_H1 + DIM + d) = a1;
  }
  red[tid]     = a0.x*a0.x + a0.y*a0.y + a0.z*a0.z + a0.w*a0.w;
  red[256+tid] = a1.x*a1.x + a1.y*a1.y + a1.z*a1.z + a1.w*a1.w;
  __syncthreads();
  for (int off = 128; off > 0; off >>= 1) {
    if (tid < off) { red[tid] += red[tid+off]; red[256+tid] += red[256+tid+off]; }
    __syncthreads();
  }
  float rq0 = rsqrtf(red[0]/DIM + EPSF);
  float rq1 = rsqrtf(red[256]/DIM + EPSF);
  float4 lw = *(const float4*)(ln2 + (size_t)l*DIM + d);
  int r = d - by*128;
  if (r >= 0 && r < 128) {
    sh[0][r] = a0.x*rq0*lw.x; sh[0][r+1] = a0.y*rq0*lw.y;
    sh[0][r+2] = a0.z*rq0*lw.z; sh[0][r+3] = a0.w*rq0*lw.w;
    sh[1][r] = a1.x*rq1*lw.x; sh[1][r+1] = a1.y*rq1*lw.y;
    sh[1][r+2] = a1.z*rq1*lw.z; sh[1][r+3] = a1.w*rq1*lw.w;
  }
  __syncthreads();

  float ag[2][4] = {}, au[2][4] = {};
  #pragma unroll
  for (int i = 0; i < 8; i++) {
    float x0 = sh[0][r0+i], x1 = sh[1][r0+i];
    ag[0][0] += x0*wg[i].x; ag[0][1] += x0*wg[i].y; ag[0][2] += x0*wg[i].z; ag[0][3] += x0*wg[i].w;
    ag[1][0] += x1*wg[i].x; ag[1][1] += x1*wg[i].y; ag[1][2] += x1*wg[i].z; ag[1][3] += x1*wg[i].w;
    au[0][0] += x0*wu[i].x; au[0][1] += x0*wu[i].y; au[0][2] += x0*wu[i].z; au[0][3] += x0*wu[i].w;
    au[1][0] += x1*wu[i].x; au[1][1] += x1*wu[i].y; au[1][2] += x1*wu[i].z; au[1][3] += x1*wu[i].w;
  }
  float* rp = red + tid*9;
  #pragma unroll
  for (int e = 0; e < 4; e++) { rp[e] = ag[0][e]; rp[4+e] = ag[1][e]; }
  __syncthreads();
  if (tid < 16) {
    float o[8] = {};
    #pragma unroll
    for (int j = 0; j < 16; j++) {
      const float* qq = red + (size_t)(j*16 + tid)*9;
      #pragma unroll
      for (int e = 0; e < 8; e++) o[e] += qq[e];
    }
    int cg = bx*64 + tid*4;
    #pragma unroll
    for (int e = 0; e < 4; e++) {
      ws[OFF_G + (by*NB + 0)*NFF + cg + e] = o[e];
      ws[OFF_G + (by*NB + 1)*NFF + cg + e] = o[4+e];
    }
  }
  __syncthreads();
  #pragma unroll
  for (int e = 0; e < 4; e++) { rp[e] = au[0][e]; rp[4+e] = au[1][e]; }
  __syncthreads();
  if (tid < 16) {
    float o[8] = {};
    #pragma unroll
    for (int j = 0; j < 16; j++) {
      const float* qq = red + (size_t)(j*16 + tid)*9;
      #pragma unroll
      for (int e = 0; e < 8; e++) o[e] += qq[e];
    }
    int cg = bx*64 + tid*4;
    #pragma unroll
    for (int e = 0; e < 4; e++) {
      ws[OFF_U + (by*NB + 0)*NFF + cg + e] = o[e];
      ws[OFF_U + (by*NB + 1)*NFF + cg + e] = o[4+e];
    }
  }
}

// ---------------- K5: swiglu slice + Wd GEMV partials -------------------------
// grid (32 colTiles(32), 8 ffSplits(384)), 256 threads
__global__ __launch_bounds__(256) void k5_mlp2(const float* __restrict__ Wd_,
    float* __restrict__ ws, int l)
{
  int bx = blockIdx.x, by = blockIdx.y;
  int tid = threadIdx.x;
  __shared__ __align__(16) float act[NB][384];
  __shared__ __align__(16) float red[256*9];

  // -- issue weight loads first --
  int ct = tid & 7, rs = tid >> 3;
  int col = bx*32 + ct*4;
  int r0 = rs*12;
  const float* Wp = Wd_ + (size_t)l*NFF*DIM + (size_t)(by*384 + r0)*DIM + col;
  float4 wb[12];
  #pragma unroll
  for (int i = 0; i < 12; i++) wb[i] = *(const float4*)(Wp + (size_t)i*DIM);

  for (int e = tid; e < 768; e += 256) {
    int b = (e >= 384);
    int loc = e - b*384;
    int ff = by*384 + loc;
    float g = 0.f, u = 0.f;
    #pragma unroll
    for (int s = 0; s < 8; s++) {
      g += ws[OFF_G + (s*NB + b)*NFF + ff];
      u += ws[OFF_U + (s*NB + b)*NFF + ff];
    }
    act[b][loc] = (g / (1.0f + __expf(-g)))*u;
  }
  __syncthreads();
  float a[2][4] = {};
  #pragma unroll
  for (int i = 0; i < 12; i++) {
    float x0 = act[0][r0+i], x1 = act[1][r0+i];
    a[0][0] += x0*wb[i].x; a[0][1] += x0*wb[i].y; a[0][2] += x0*wb[i].z; a[0][3] += x0*wb[i].w;
    a[1][0] += x1*wb[i].x; a[1][1] += x1*wb[i].y; a[1][2] += x1*wb[i].z; a[1][3] += x1*wb[i].w;
  }
  float* rp = red + tid*9;
  #pragma unroll
  for (int e = 0; e < 4; e++) { rp[e] = a[0][e]; rp[4+e] = a[1][e]; }
  __syncthreads();
  if (tid < 8) {
    float o[8] = {};
    #pragma unroll
    for (int j = 0; j < 32; j++) {
      const float* qq = red + (size_t)(j*8 + tid)*9;
      #pragma unroll
      for (int e = 0; e < 8; e++) o[e] += qq[e];
    }
    int cg = bx*32 + tid*4;
    #pragma unroll
    for (int e = 0; e < 4; e++) {
      ws[OFF_WD + (by*NB + 0)*DIM + cg + e] = o[e];
      ws[OFF_WD + (by*NB + 1)*DIM + cg + e] = o[4+e];
    }
  }
}

// ---------------- K6: final h + rmsnorm + lm_head GEMV ------------------------
// grid 2374 blocks (64 cols each), 256 threads
__global__ __launch_bounds__(256) void k6_lmhead(const float* __restrict__ lmw,
    const float* __restrict__ fnw, const float* __restrict__ ws,
    float* __restrict__ out)
{
  __shared__ __align__(16) float nf[NB*DIM];
  __shared__ __align__(16) float red[256*9];
  int tid = threadIdx.x;
  int d = tid*4;
  float4 a0 = *(const float4*)(ws + OFF_H1 + d);
  float4 a1 = *(const float4*)(ws + OFF_H1 + DIM + d);
  #pragma unroll
  for (int s = 0; s < 8; s++) {
    float4 p0 = *(const float4*)(ws + OFF_WD + (s*NB + 0)*DIM + d);
    float4 p1 = *(const float4*)(ws + OFF_WD + (s*NB + 1)*DIM + d);
    a0.x += p0.x; a0.y += p0.y; a0.z += p0.z; a0.w += p0.w;
    a1.x += p1.x; a1.y += p1.y; a1.z += p1.z; a1.w += p1.w;
  }
  red[tid]     = a0.x*a0.x + a0.y*a0.y + a0.z*a0.z + a0.w*a0.w;
  red[256+tid] = a1.x*a1.x + a1.y*a1.y + a1.z*a1.z + a1.w*a1.w;
  __syncthreads();
  for (int off = 128; off > 0; off >>= 1) {
    if (tid < off) { red[tid] += red[tid+off]; red[256+tid] += red[256+tid+off]; }
    __syncthreads();
  }
  float rq0 = rsqrtf(red[0]/DIM + EPSF);
  float rq1 = rsqrtf(red[256]/DIM + EPSF);
  float4 fw = *(const float4*)(fnw + d);
  nf[d]   = a0.x*rq0*fw.x; nf[d+1] = a0.y*rq0*fw.y;
  nf[d+2] = a0.z*rq0*fw.z; nf[d+3] = a0.w*rq0*fw.w;
  nf[DIM+d]   = a1.x*rq1*fw.x; nf[DIM+d+1] = a1.y*rq1*fw.y;
  nf[DIM+d+2] = a1.z*rq1*fw.z; nf[DIM+d+3] = a1.w*rq1*fw.w;
  __syncthreads();

  int ct = tid & 15, rs = tid >> 4;
  int col = blockIdx.x*64 + ct*4;
  const float* Wp = lmw + (size_t)(rs*64)*NVOCAB + col;
  float a[2][4] = {};
  for (int t = 0; t < 8; t++) {
    float4 wb[8];
    #pragma unroll
    for (int i = 0; i < 8; i++)
      wb[i] = *(const float4*)(Wp + (size_t)(t*8 + i)*NVOCAB);
    #pragma unroll
    for (int i = 0; i < 8; i++) {
      int rr = rs*64 + t*8 + i;
      float x0 = nf[rr], x1 = nf[DIM+rr];
      a[0][0] += x0*wb[i].x; a[0][1] += x0*wb[i].y; a[0][2] += x0*wb[i].z; a[0][3] += x0*wb[i].w;
      a[1][0] += x1*wb[i].x; a[1][1] += x1*wb[i].y; a[1][2] += x1*wb[i].z; a[1][3] += x1*wb[i].w;
    }
  }
  float* rp = red + tid*9;
  #pragma unroll
  for (int e = 0; e < 4; e++) { rp[e] = a[0][e]; rp[4+e] = a[1][e]; }
  __syncthreads();
  if (tid < 16) {
    float o[8] = {};
    #pragma unroll
    for (int j = 0; j < 16; j++) {
      const float* qq = red + (size_t)(j*16 + tid)*9;
      #pragma unroll
      for (int e = 0; e < 8; e++) o[e] += qq[e];
    }
    int cg = blockIdx.x*64 + tid*4;
    #pragma unroll
    for (int e = 0; e < 4; e++) {
      out[cg + e] = o[e];
      out[NVOCAB + cg + e] = o[4+e];
    }
  }
}

extern "C" void kernel_launch(void* const* d_in, const int* in_sizes, int n_in,
                              void* d_out, int out_size, void* d_ws, size_t ws_size,
                              hipStream_t stream) {
  (void)in_sizes; (void)n_in; (void)out_size; (void)ws_size;
  const float* embeds = (const float*)d_in[0];
  const int*   posids = (const int*)d_in[1];
  const float* pastK  = (const float*)d_in[2];
  const float* pastV  = (const float*)d_in[3];
  const float* Wq     = (const float*)d_in[4];
  const float* Wk     = (const float*)d_in[5];
  const float* Wv     = (const float*)d_in[6];
  const float* Wo     = (const float*)d_in[7];
  const float* Wg     = (const float*)d_in[8];
  const float* Wu     = (const float*)d_in[9];
  const float* Wd     = (const float*)d_in[10];
  const float* ln1    = (const float*)d_in[11];
  const float* ln2    = (const float*)d_in[12];
  const float* qnw    = (const float*)d_in[13];
  const float* knw    = (const float*)d_in[14];
  const float* fnw    = (const float*)d_in[15];
  const float* lmw    = (const float*)d_in[16];
  float* out = (float*)d_out;
  float* ws  = (float*)d_ws;

  k0_init<<<1, 256, 0, stream>>>(embeds, ln1, ws);
  for (int l = 0; l < NL; l++) {
    k1_qkv <<<dim3(64, 8), 256, 0, stream>>>(Wq, Wk, Wv, ln1, ws, l);
    k2_attn<<<dim3(SCH, NHKV, NB), 256, 0, stream>>>(pastK, pastV, posids, qnw, knw, out, ws, l);
    k3_wo  <<<dim3(32, 8), 256, 0, stream>>>(Wo, ws, l);
    k4_mlp1<<<dim3(48, 8), 256, 0, stream>>>(Wg, Wu, ln2, ws, l);
    k5_mlp2<<<dim3(32, 8), 256, 0, stream>>>(Wd, ws, l);
  }
  k6_lmhead<<<NVOCAB/64, 256, 0, stream>>>(lmw, fnw, ws, out);
}

// Round 5
// 1406.013 us; speedup vs baseline: 3.9777x; 1.0457x over previous
//
#include <hip/hip_runtime.h>
#include <math.h>

#define NL 28
#define DIM 1024
#define NHQ 16
#define NHKV 8
#define HDIM 128
#define NG 2
#define NFF 3072
#define NVOCAB 151936
#define NB 2
#define NPAST 1024
#define NPTOT 1025
#define EPSF 1e-6f
#define QKSCALE 0.08838834764831845f
#define LOGTHETA 13.815510557964274f

#define SQKV 8
#define SCH 32

// ws offsets (floats)
#define OFF_N1   0        // [NB][1024] rmsnorm(embeds)*ln1[0] (layer-0 only)
#define OFF_H    2048     // [NB][1024] residual h entering current layer
#define OFF_H1   4096     // [NB][1024] h after attn residual
#define OFF_QKV  8192     // [8][NB][4096] qkv partials
#define OFF_AM   73728    // [NB*16][32] chunk max
#define OFF_AL   74752    // [NB*16][32] chunk sumexp
#define OFF_AO   75776    // [NB*16][32][128] chunk weighted-V
#define OFF_WO   206848   // [8][NB][1024] Wo partials
#define OFF_G    223232   // [8][NB][3072]
#define OFF_U    272384   // [8][NB][3072]
#define OFF_WD   321536   // [8][NB][1024]

#define PK_OFF ((size_t)NB*NVOCAB)
#define PV_OFF (PK_OFF + (size_t)NL*NB*NHKV*NPTOT*HDIM)

__device__ __forceinline__ float wave_red_sum(float v) {
  #pragma unroll
  for (int off = 32; off > 0; off >>= 1) v += __shfl_xor(v, off);
  return v;
}

// ---------------- K0: n1 = rmsnorm(embeds)*ln1[0]; h = embeds -----------------
__global__ __launch_bounds__(256) void k0_init(const float* __restrict__ embeds,
    const float* __restrict__ ln1, float* __restrict__ ws)
{
  int tid = threadIdx.x;
  int lane = tid & 63, w = tid >> 6;
  __shared__ float wr[8];
  int d = tid*4;
  float4 v0 = *(const float4*)(embeds + d);
  float4 v1 = *(const float4*)(embeds + DIM + d);
  float4 lw = *(const float4*)(ln1 + d);
  *(float4*)(ws + OFF_H + d) = v0;
  *(float4*)(ws + OFF_H + DIM + d) = v1;
  float s0 = wave_red_sum(v0.x*v0.x + v0.y*v0.y + v0.z*v0.z + v0.w*v0.w);
  float s1 = wave_red_sum(v1.x*v1.x + v1.y*v1.y + v1.z*v1.z + v1.w*v1.w);
  if (lane == 0) { wr[w] = s0; wr[4+w] = s1; }
  __syncthreads();
  float r0 = rsqrtf((wr[0]+wr[1]+wr[2]+wr[3])/DIM + EPSF);
  float r1 = rsqrtf((wr[4]+wr[5]+wr[6]+wr[7])/DIM + EPSF);
  float4 n0 = make_float4(v0.x*r0*lw.x, v0.y*r0*lw.y, v0.z*r0*lw.z, v0.w*r0*lw.w);
  float4 n1 = make_float4(v1.x*r1*lw.x, v1.y*r1*lw.y, v1.z*r1*lw.z, v1.w*r1*lw.w);
  *(float4*)(ws + OFF_N1 + d) = n0;
  *(float4*)(ws + OFF_N1 + DIM + d) = n1;
}

// ---------------- K1: [l>0: h2/n1 recompute] + QKV GEMV partials --------------
// grid (64 colTiles(64), 8 rowSplits(128)), 256 threads
__global__ __launch_bounds__(256) void k1_qkv(
    const float* __restrict__ Wq_, const float* __restrict__ Wk_,
    const float* __restrict__ Wv_, const float* __restrict__ ln1,
    float* __restrict__ ws, int l)
{
  int bx = blockIdx.x, by = blockIdx.y;
  int tid = threadIdx.x;
  int lane = tid & 63, w = tid >> 6;
  __shared__ __align__(16) float sh[NB][128];
  __shared__ __align__(16) float red[256*9];
  __shared__ float wr[8];

  int ct = tid & 15, rs = tid >> 4;
  int colg = bx*64 + ct*4;
  const float* W; int O; int wcol;
  if (bx < 32)      { W = Wq_; O = 2048; wcol = colg; }
  else if (bx < 48) { W = Wk_; O = 1024; wcol = colg - 2048; }
  else              { W = Wv_; O = 1024; wcol = colg - 3072; }
  int r0 = rs*8;
  const float* Wp = W + (size_t)l*DIM*O + (size_t)(by*128 + r0)*O + wcol;
  float4 wb[8];

  if (l == 0) {
    int b = tid >> 7, r = tid & 127;
    float nv = ws[OFF_N1 + b*DIM + by*128 + r];
    __builtin_amdgcn_sched_barrier(0);
    #pragma unroll
    for (int i = 0; i < 8; i++) wb[i] = *(const float4*)(Wp + (size_t)i*O);
    sh[b][r] = nv;
    __syncthreads();
  } else {
    // (a) preamble loads first: H1 + WD partials + ln1 slice
    int d = tid*4;
    float4 a0 = *(const float4*)(ws + OFF_H1 + d);
    float4 a1 = *(const float4*)(ws + OFF_H1 + DIM + d);
    #pragma unroll
    for (int s = 0; s < 8; s++) {
      float4 p0 = *(const float4*)(ws + OFF_WD + (s*NB + 0)*DIM + d);
      float4 p1 = *(const float4*)(ws + OFF_WD + (s*NB + 1)*DIM + d);
      a0.x += p0.x; a0.y += p0.y; a0.z += p0.z; a0.w += p0.w;
      a1.x += p1.x; a1.y += p1.y; a1.z += p1.z; a1.w += p1.w;
    }
    float4 lw = *(const float4*)(ln1 + (size_t)l*DIM + d);
    __builtin_amdgcn_sched_barrier(0);
    // (b) weight stream
    #pragma unroll
    for (int i = 0; i < 8; i++) wb[i] = *(const float4*)(Wp + (size_t)i*O);
    // (c) preamble compute (overlaps weight stream)
    if (bx == 0 && by == 0) {
      *(float4*)(ws + OFF_H + d) = a0;
      *(float4*)(ws + OFF_H + DIM + d) = a1;
    }
    float s0 = wave_red_sum(a0.x*a0.x + a0.y*a0.y + a0.z*a0.z + a0.w*a0.w);
    float s1 = wave_red_sum(a1.x*a1.x + a1.y*a1.y + a1.z*a1.z + a1.w*a1.w);
    if (lane == 0) { wr[w] = s0; wr[4+w] = s1; }
    __syncthreads();
    float rq0 = rsqrtf((wr[0]+wr[1]+wr[2]+wr[3])/DIM + EPSF);
    float rq1 = rsqrtf((wr[4]+wr[5]+wr[6]+wr[7])/DIM + EPSF);
    int r = d - by*128;
    if (r >= 0 && r < 128) {
      sh[0][r] = a0.x*rq0*lw.x; sh[0][r+1] = a0.y*rq0*lw.y;
      sh[0][r+2] = a0.z*rq0*lw.z; sh[0][r+3] = a0.w*rq0*lw.w;
      sh[1][r] = a1.x*rq1*lw.x; sh[1][r+1] = a1.y*rq1*lw.y;
      sh[1][r+2] = a1.z*rq1*lw.z; sh[1][r+3] = a1.w*rq1*lw.w;
    }
    __syncthreads();
  }

  float a[2][4] = {};
  #pragma unroll
  for (int i = 0; i < 8; i++) {
    float x0 = sh[0][r0+i], x1 = sh[1][r0+i];
    a[0][0] += x0*wb[i].x; a[0][1] += x0*wb[i].y; a[0][2] += x0*wb[i].z; a[0][3] += x0*wb[i].w;
    a[1][0] += x1*wb[i].x; a[1][1] += x1*wb[i].y; a[1][2] += x1*wb[i].z; a[1][3] += x1*wb[i].w;
  }
  float* rp = red + tid*9;
  #pragma unroll
  for (int e = 0; e < 4; e++) { rp[e] = a[0][e]; rp[4+e] = a[1][e]; }
  __syncthreads();
  if (tid < 16) {
    float o[8] = {};
    #pragma unroll
    for (int j = 0; j < 16; j++) {
      const float* q = red + (size_t)(j*16 + tid)*9;
      #pragma unroll
      for (int e = 0; e < 8; e++) o[e] += q[e];
    }
    int cg = bx*64 + tid*4;
    #pragma unroll
    for (int e = 0; e < 4; e++) {
      ws[OFF_QKV + (by*NB + 0)*4096 + cg + e] = o[e];
      ws[OFF_QKV + (by*NB + 1)*4096 + cg + e] = o[4+e];
    }
  }
}

// ---------------- K2: qkv finalize + qknorm + rope + KV copy + chunk attention
// grid (32 chunks, NHKV, NB), 256 threads
__global__ __launch_bounds__(256) void k2_attn(
    const float* __restrict__ pastK, const float* __restrict__ pastV,
    const int* __restrict__ posids, const float* __restrict__ qnw,
    const float* __restrict__ knw, float* __restrict__ out,
    float* __restrict__ ws, int l)
{
  int c = blockIdx.x, kv = blockIdx.y, b = blockIdx.z;
  int tid = threadIdx.x;
  int lane = tid & 63, w = tid >> 6;
  int g = tid >> 7, o = tid & 127;
  __shared__ __align__(16) float qf[NG][HDIM];
  __shared__ __align__(16) float kf[HDIM];
  __shared__ __align__(16) float vf[HDIM];
  __shared__ __align__(16) float pre[NG][HDIM];
  __shared__ __align__(16) float kpre[HDIM];
  __shared__ __align__(16) float po[8][NG][HDIM];
  __shared__ float wr[8];
  __shared__ float pm[8][NG], pl[8][NG];

  // (a) preamble loads: qkv partials + norm weights + pos
  int hq = kv*NG + g;
  float qp = 0.f, kp = 0.f;
  #pragma unroll
  for (int s = 0; s < SQKV; s++) qp += ws[OFF_QKV + (s*NB + b)*4096 + hq*HDIM + o];
  int kvslot = g ? 3072 : 2048;
  #pragma unroll
  for (int s = 0; s < SQKV; s++) kp += ws[OFF_QKV + (s*NB + b)*4096 + kvslot + kv*HDIM + o];
  float qw_ = qnw[l*HDIM + o];
  float kw_ = knw[l*HDIM + o];
  float pos = (float)posids[b];
  __builtin_amdgcn_sched_barrier(0);

  // (b) KV stream prefetch for this chunk (independent of preamble)
  int grp = tid >> 5, q = tid & 31;
  int p0 = c*32;
  int p1 = (c == SCH-1) ? NPTOT : p0 + 32;
  size_t pastbase = ((((size_t)l*NB + b)*NHKV + kv)*NPAST)*HDIM;
  size_t presbase = ((((size_t)l*NB + b)*NHKV + kv)*NPTOT)*HDIM;
  float4 kk[5], vv[5];
  int ns = 0;
  for (int p = p0 + grp; p < p1; p += 8) {
    if (p < NPAST) {
      kk[ns] = *(const float4*)(pastK + pastbase + (size_t)p*HDIM + q*4);
      vv[ns] = *(const float4*)(pastV + pastbase + (size_t)p*HDIM + q*4);
    }
    ns++;
  }
  __builtin_amdgcn_sched_barrier(0);

  // (c) preamble compute: qknorm + rope (overlaps KV stream)
  float sq = wave_red_sum(qp*qp);
  float sk = wave_red_sum(kp*kp);
  if (lane == 0) { wr[w] = sq; wr[4+w] = sk; }
  __syncthreads();
  float qss = wr[g<<1] + wr[(g<<1)+1];
  float qr = rsqrtf(qss/HDIM + EPSF);
  float kss = wr[4] + wr[5];
  float kr = rsqrtf(kss/HDIM + EPSF);
  float qn = qp*qr*qw_;
  pre[g][o] = qn;
  if (g == 0) kpre[o] = kp*kr*kw_;
  else vf[o] = kp;
  __syncthreads();
  float ang = pos * expf(-(2.0f*(float)(o & 63)/(float)HDIM)*LOGTHETA);
  float sn, cs;
  sincosf(ang, &sn, &cs);
  {
    float rotq = (o < 64) ? -pre[g][o+64] : pre[g][o-64];
    qf[g][o] = qn*cs + rotq*sn;
    if (g == 0) {
      float kx = kpre[o];
      float rotk = (o < 64) ? -kpre[o+64] : kpre[o-64];
      kf[o] = kx*cs + rotk*sn;
    }
  }
  __syncthreads();

  // (d) scores + KV copy
  float4 q0 = *(const float4*)&qf[0][q*4];
  float4 q1 = *(const float4*)&qf[1][q*4];
  float sc0[5], sc1[5];
  int i = 0;
  for (int p = p0 + grp; p < p1; p += 8, i++) {
    float4 k4, v4;
    if (p < NPAST) { k4 = kk[i]; v4 = vv[i]; }
    else { k4 = *(const float4*)&kf[q*4]; v4 = *(const float4*)&vf[q*4]; vv[i] = v4; }
    *(float4*)(out + PK_OFF + presbase + (size_t)p*HDIM + q*4) = k4;
    *(float4*)(out + PV_OFF + presbase + (size_t)p*HDIM + q*4) = v4;
    float d0 = q0.x*k4.x + q0.y*k4.y + q0.z*k4.z + q0.w*k4.w;
    float d1 = q1.x*k4.x + q1.y*k4.y + q1.z*k4.z + q1.w*k4.w;
    #pragma unroll
    for (int off = 16; off > 0; off >>= 1) {
      d0 += __shfl_xor(d0, off);
      d1 += __shfl_xor(d1, off);
    }
    sc0[i] = d0*QKSCALE; sc1[i] = d1*QKSCALE;
  }
  float m0 = -1e30f, m1 = -1e30f;
  for (int j = 0; j < i; j++) { m0 = fmaxf(m0, sc0[j]); m1 = fmaxf(m1, sc1[j]); }
  if (q == 0) { pm[grp][0] = m0; pm[grp][1] = m1; }
  __syncthreads();
  float M0 = -1e30f, M1 = -1e30f;
  #pragma unroll
  for (int j = 0; j < 8; j++) { M0 = fmaxf(M0, pm[j][0]); M1 = fmaxf(M1, pm[j][1]); }
  float l0 = 0.f, l1 = 0.f;
  float4 o0 = {0,0,0,0}, o1 = {0,0,0,0};
  for (int j = 0; j < i; j++) {
    float w0 = __expf(sc0[j] - M0), w1 = __expf(sc1[j] - M1);
    l0 += w0; l1 += w1;
    o0.x += w0*vv[j].x; o0.y += w0*vv[j].y; o0.z += w0*vv[j].z; o0.w += w0*vv[j].w;
    o1.x += w1*vv[j].x; o1.y += w1*vv[j].y; o1.z += w1*vv[j].z; o1.w += w1*vv[j].w;
  }
  if (q == 0) { pl[grp][0] = l0; pl[grp][1] = l1; }
  *(float4*)&po[grp][0][q*4] = o0;
  *(float4*)&po[grp][1][q*4] = o1;
  __syncthreads();
  {
    int head = tid >> 7, dd = tid & 127;
    float acc = 0.f;
    #pragma unroll
    for (int j = 0; j < 8; j++) acc += po[j][head][dd];
    int base = ((b*NHKV + kv)*NG + head)*SCH + c;
    ws[OFF_AO + (size_t)base*HDIM + dd] = acc;
    if (dd == 0) {
      float ll = 0.f;
      #pragma unroll
      for (int j = 0; j < 8; j++) ll += pl[j][head];
      ws[OFF_AM + base] = (head ? M1 : M0);
      ws[OFF_AL + base] = ll;
    }
  }
}

// ---------------- K3: softmax combine + Wo GEMV partials ----------------------
// grid (32 colTiles(32), 8 headPairs(256 rows)), 256 threads
__global__ __launch_bounds__(256) void k3_wo(const float* __restrict__ Wo_,
    float* __restrict__ ws, int l)
{
  int bx = blockIdx.x, by = blockIdx.y;
  int tid = threadIdx.x;
  __shared__ __align__(16) float x[NB][256];
  __shared__ float wf[NB][2][SCH];
  __shared__ float invL[NB][2];
  __shared__ __align__(16) float red[256*9];

  // (a) m/l finalize, parallel across 128 threads (one 32-lane group per (b,hh))
  if (tid < 128) {
    int b = tid >> 6, hh = (tid >> 5) & 1, cc = tid & 31;
    int hb = b*16 + by*2 + hh;
    float m  = ws[OFF_AM + hb*SCH + cc];
    float ll = ws[OFF_AL + hb*SCH + cc];
    float M = m;
    #pragma unroll
    for (int off = 16; off > 0; off >>= 1) M = fmaxf(M, __shfl_xor(M, off));
    float f = __expf(m - M);
    float Ls = ll*f;
    #pragma unroll
    for (int off = 16; off > 0; off >>= 1) Ls += __shfl_xor(Ls, off);
    wf[b][hh][cc] = f;
    if (cc == 0) invL[b][hh] = 1.0f/Ls;
  }
  __builtin_amdgcn_sched_barrier(0);

  // (b) weight stream
  int ct = tid & 7, rs = tid >> 3;
  int col = bx*32 + ct*4;
  int r0 = rs*8;
  const float* Wp = Wo_ + (size_t)l*(NHQ*HDIM)*DIM + (size_t)(by*256 + r0)*DIM + col;
  float4 wb[8];
  #pragma unroll
  for (int i = 0; i < 8; i++) wb[i] = *(const float4*)(Wp + (size_t)i*DIM);
  __syncthreads();

  // (c) x combine (AO stream overlaps weight stream)
  for (int e = tid; e < 512; e += 256) {
    int b = e >> 8, rr = e & 255, hh = rr >> 7, dd = rr & 127;
    int hb = b*16 + by*2 + hh;
    const float* op = ws + OFF_AO + (size_t)(hb*SCH)*HDIM + dd;
    float acc = 0.f;
    #pragma unroll
    for (int cc = 0; cc < SCH; cc++) acc += op[(size_t)cc*HDIM]*wf[b][hh][cc];
    x[b][rr] = acc*invL[b][hh];
  }
  __syncthreads();
  float a[2][4] = {};
  #pragma unroll
  for (int i = 0; i < 8; i++) {
    float x0 = x[0][r0+i], x1 = x[1][r0+i];
    a[0][0] += x0*wb[i].x; a[0][1] += x0*wb[i].y; a[0][2] += x0*wb[i].z; a[0][3] += x0*wb[i].w;
    a[1][0] += x1*wb[i].x; a[1][1] += x1*wb[i].y; a[1][2] += x1*wb[i].z; a[1][3] += x1*wb[i].w;
  }
  float* rp = red + tid*9;
  #pragma unroll
  for (int e = 0; e < 4; e++) { rp[e] = a[0][e]; rp[4+e] = a[1][e]; }
  __syncthreads();
  if (tid < 8) {
    float o[8] = {};
    #pragma unroll
    for (int j = 0; j < 32; j++) {
      const float* qq = red + (size_t)(j*8 + tid)*9;
      #pragma unroll
      for (int e = 0; e < 8; e++) o[e] += qq[e];
    }
    int cg = bx*32 + tid*4;
    #pragma unroll
    for (int e = 0; e < 4; e++) {
      ws[OFF_WO + (by*NB + 0)*DIM + cg + e] = o[e];
      ws[OFF_WO + (by*NB + 1)*DIM + cg + e] = o[4+e];
    }
  }
}

// ---------------- K4: h1+n2 recompute + Wg/Wu GEMV partials -------------------
// grid (48 colTiles(64), 8 rowSplits(128)), 256 threads
__global__ __launch_bounds__(256) void k4_mlp1(const float* __restrict__ Wg_,
    const float* __restrict__ Wu_, const float* __restrict__ ln2,
    float* __restrict__ ws, int l)
{
  int bx = blockIdx.x, by = blockIdx.y;
  int tid = threadIdx.x;
  int lane = tid & 63, w = tid >> 6;
  __shared__ __align__(16) float sh[NB][128];
  __shared__ __align__(16) float red[256*9];
  __shared__ float wr[8];

  // (a) preamble loads first
  int d = tid*4;
  float4 a0 = *(const float4*)(ws + OFF_H + d);
  float4 a1 = *(const float4*)(ws + OFF_H + DIM + d);
  #pragma unroll
  for (int s = 0; s < 8; s++) {
    float4 p0 = *(const float4*)(ws + OFF_WO + (s*NB + 0)*DIM + d);
    float4 p1 = *(const float4*)(ws + OFF_WO + (s*NB + 1)*DIM + d);
    a0.x += p0.x; a0.y += p0.y; a0.z += p0.z; a0.w += p0.w;
    a1.x += p1.x; a1.y += p1.y; a1.z += p1.z; a1.w += p1.w;
  }
  float4 lw = *(const float4*)(ln2 + (size_t)l*DIM + d);
  __builtin_amdgcn_sched_barrier(0);

  // (b) weight stream
  int ct = tid & 15, rs = tid >> 4;
  int col = bx*64 + ct*4;
  int r0 = rs*8;
  const float* Wgp = Wg_ + (size_t)l*DIM*NFF + (size_t)(by*128 + r0)*NFF + col;
  const float* Wup = Wu_ + (size_t)l*DIM*NFF + (size_t)(by*128 + r0)*NFF + col;
  float4 wg[8], wu[8];
  #pragma unroll
  for (int i = 0; i < 8; i++) {
    wg[i] = *(const float4*)(Wgp + (size_t)i*NFF);
    wu[i] = *(const float4*)(Wup + (size_t)i*NFF);
  }

  // (c) preamble compute
  if (bx == 0 && by == 0) {
    *(float4*)(ws + OFF_H1 + d) = a0;
    *(float4*)(ws + OFF_H1 + DIM + d) = a1;
  }
  float s0 = wave_red_sum(a0.x*a0.x + a0.y*a0.y + a0.z*a0.z + a0.w*a0.w);
  float s1 = wave_red_sum(a1.x*a1.x + a1.y*a1.y + a1.z*a1.z + a1.w*a1.w);
  if (lane == 0) { wr[w] = s0; wr[4+w] = s1; }
  __syncthreads();
  float rq0 = rsqrtf((wr[0]+wr[1]+wr[2]+wr[3])/DIM + EPSF);
  float rq1 = rsqrtf((wr[4]+wr[5]+wr[6]+wr[7])/DIM + EPSF);
  int r = d - by*128;
  if (r >= 0 && r < 128) {
    sh[0][r] = a0.x*rq0*lw.x; sh[0][r+1] = a0.y*rq0*lw.y;
    sh[0][r+2] = a0.z*rq0*lw.z; sh[0][r+3] = a0.w*rq0*lw.w;
    sh[1][r] = a1.x*rq1*lw.x; sh[1][r+1] = a1.y*rq1*lw.y;
    sh[1][r+2] = a1.z*rq1*lw.z; sh[1][r+3] = a1.w*rq1*lw.w;
  }
  __syncthreads();

  float ag[2][4] = {}, au[2][4] = {};
  #pragma unroll
  for (int i = 0; i < 8; i++) {
    float x0 = sh[0][r0+i], x1 = sh[1][r0+i];
    ag[0][0] += x0*wg[i].x; ag[0][1] += x0*wg[i].y; ag[0][2] += x0*wg[i].z; ag[0][3] += x0*wg[i].w;
    ag[1][0] += x1*wg[i].x; ag[1][1] += x1*wg[i].y; ag[1][2] += x1*wg[i].z; ag[1][3] += x1*wg[i].w;
    au[0][0] += x0*wu[i].x; au[0][1] += x0*wu[i].y; au[0][2] += x0*wu[i].z; au[0][3] += x0*wu[i].w;
    au[1][0] += x1*wu[i].x; au[1][1] += x1*wu[i].y; au[1][2] += x1*wu[i].z; au[1][3] += x1*wu[i].w;
  }
  float* rp = red + tid*9;
  #pragma unroll
  for (int e = 0; e < 4; e++) { rp[e] = ag[0][e]; rp[4+e] = ag[1][e]; }
  __syncthreads();
  if (tid < 16) {
    float o[8] = {};
    #pragma unroll
    for (int j = 0; j < 16; j++) {
      const float* qq = red + (size_t)(j*16 + tid)*9;
      #pragma unroll
      for (int e = 0; e < 8; e++) o[e] += qq[e];
    }
    int cg = bx*64 + tid*4;
    #pragma unroll
    for (int e = 0; e < 4; e++) {
      ws[OFF_G + (by*NB + 0)*NFF + cg + e] = o[e];
      ws[OFF_G + (by*NB + 1)*NFF + cg + e] = o[4+e];
    }
  }
  __syncthreads();
  #pragma unroll
  for (int e = 0; e < 4; e++) { rp[e] = au[0][e]; rp[4+e] = au[1][e]; }
  __syncthreads();
  if (tid < 16) {
    float o[8] = {};
    #pragma unroll
    for (int j = 0; j < 16; j++) {
      const float* qq = red + (size_t)(j*16 + tid)*9;
      #pragma unroll
      for (int e = 0; e < 8; e++) o[e] += qq[e];
    }
    int cg = bx*64 + tid*4;
    #pragma unroll
    for (int e = 0; e < 4; e++) {
      ws[OFF_U + (by*NB + 0)*NFF + cg + e] = o[e];
      ws[OFF_U + (by*NB + 1)*NFF + cg + e] = o[4+e];
    }
  }
}

// ---------------- K5: swiglu slice + Wd GEMV partials -------------------------
// grid (32 colTiles(32), 8 ffSplits(384)), 256 threads
__global__ __launch_bounds__(256) void k5_mlp2(const float* __restrict__ Wd_,
    float* __restrict__ ws, int l)
{
  int bx = blockIdx.x, by = blockIdx.y;
  int tid = threadIdx.x;
  __shared__ __align__(16) float act[NB][384];
  __shared__ __align__(16) float red[256*9];

  // (a) preamble loads: G/U partials (float4), 192 active threads
  float4 gacc = {0,0,0,0}, uacc = {0,0,0,0};
  int pb = 0, pf4 = 0;
  if (tid < 192) {
    pb = tid / 96; pf4 = tid % 96;
    int f4 = (by*384)/4 + pf4;
    const float4* Gp = (const float4*)(ws + OFF_G);
    const float4* Up = (const float4*)(ws + OFF_U);
    #pragma unroll
    for (int s = 0; s < 8; s++) {
      float4 g4 = Gp[(size_t)(s*NB + pb)*(NFF/4) + f4];
      float4 u4 = Up[(size_t)(s*NB + pb)*(NFF/4) + f4];
      gacc.x += g4.x; gacc.y += g4.y; gacc.z += g4.z; gacc.w += g4.w;
      uacc.x += u4.x; uacc.y += u4.y; uacc.z += u4.z; uacc.w += u4.w;
    }
  }
  __builtin_amdgcn_sched_barrier(0);

  // (b) weight stream
  int ct = tid & 7, rs = tid >> 3;
  int col = bx*32 + ct*4;
  int r0 = rs*12;
  const float* Wp = Wd_ + (size_t)l*NFF*DIM + (size_t)(by*384 + r0)*DIM + col;
  float4 wb[12];
  #pragma unroll
  for (int i = 0; i < 12; i++) wb[i] = *(const float4*)(Wp + (size_t)i*DIM);

  // (c) swiglu + LDS store
  if (tid < 192) {
    float4 r;
    r.x = (gacc.x / (1.0f + __expf(-gacc.x)))*uacc.x;
    r.y = (gacc.y / (1.0f + __expf(-gacc.y)))*uacc.y;
    r.z = (gacc.z / (1.0f + __expf(-gacc.z)))*uacc.z;
    r.w = (gacc.w / (1.0f + __expf(-gacc.w)))*uacc.w;
    *(float4*)&act[pb][pf4*4] = r;
  }
  __syncthreads();

  float a[2][4] = {};
  #pragma unroll
  for (int i = 0; i < 12; i++) {
    float x0 = act[0][r0+i], x1 = act[1][r0+i];
    a[0][0] += x0*wb[i].x; a[0][1] += x0*wb[i].y; a[0][2] += x0*wb[i].z; a[0][3] += x0*wb[i].w;
    a[1][0] += x1*wb[i].x; a[1][1] += x1*wb[i].y; a[1][2] += x1*wb[i].z; a[1][3] += x1*wb[i].w;
  }
  float* rp = red + tid*9;
  #pragma unroll
  for (int e = 0; e < 4; e++) { rp[e] = a[0][e]; rp[4+e] = a[1][e]; }
  __syncthreads();
  if (tid < 8) {
    float o[8] = {};
    #pragma unroll
    for (int j = 0; j < 32; j++) {
      const float* qq = red + (size_t)(j*8 + tid)*9;
      #pragma unroll
      for (int e = 0; e < 8; e++) o[e] += qq[e];
    }
    int cg = bx*32 + tid*4;
    #pragma unroll
    for (int e = 0; e < 4; e++) {
      ws[OFF_WD + (by*NB + 0)*DIM + cg + e] = o[e];
      ws[OFF_WD + (by*NB + 1)*DIM + cg + e] = o[4+e];
    }
  }
}

// ---------------- K6: final h + rmsnorm + lm_head GEMV ------------------------
// grid 2374 blocks (64 cols each), 256 threads
__global__ __launch_bounds__(256) void k6_lmhead(const float* __restrict__ lmw,
    const float* __restrict__ fnw, const float* __restrict__ ws,
    float* __restrict__ out)
{
  __shared__ __align__(16) float nf[NB*DIM];
  __shared__ __align__(16) float red[256*9];
  __shared__ float wr[8];
  int tid = threadIdx.x;
  int lane = tid & 63, w = tid >> 6;

  // (a) preamble loads
  int d = tid*4;
  float4 a0 = *(const float4*)(ws + OFF_H1 + d);
  float4 a1 = *(const float4*)(ws + OFF_H1 + DIM + d);
  #pragma unroll
  for (int s = 0; s < 8; s++) {
    float4 p0 = *(const float4*)(ws + OFF_WD + (s*NB + 0)*DIM + d);
    float4 p1 = *(const float4*)(ws + OFF_WD + (s*NB + 1)*DIM + d);
    a0.x += p0.x; a0.y += p0.y; a0.z += p0.z; a0.w += p0.w;
    a1.x += p1.x; a1.y += p1.y; a1.z += p1.z; a1.w += p1.w;
  }
  float4 fw = *(const float4*)(fnw + d);
  __builtin_amdgcn_sched_barrier(0);

  float s0 = wave_red_sum(a0.x*a0.x + a0.y*a0.y + a0.z*a0.z + a0.w*a0.w);
  float s1 = wave_red_sum(a1.x*a1.x + a1.y*a1.y + a1.z*a1.z + a1.w*a1.w);
  if (lane == 0) { wr[w] = s0; wr[4+w] = s1; }
  __syncthreads();
  float rq0 = rsqrtf((wr[0]+wr[1]+wr[2]+wr[3])/DIM + EPSF);
  float rq1 = rsqrtf((wr[4]+wr[5]+wr[6]+wr[7])/DIM + EPSF);
  nf[d]   = a0.x*rq0*fw.x; nf[d+1] = a0.y*rq0*fw.y;
  nf[d+2] = a0.z*rq0*fw.z; nf[d+3] = a0.w*rq0*fw.w;
  nf[DIM+d]   = a1.x*rq1*fw.x; nf[DIM+d+1] = a1.y*rq1*fw.y;
  nf[DIM+d+2] = a1.z*rq1*fw.z; nf[DIM+d+3] = a1.w*rq1*fw.w;
  __syncthreads();

  int ct = tid & 15, rs = tid >> 4;
  int col = blockIdx.x*64 + ct*4;
  const float* Wp = lmw + (size_t)(rs*64)*NVOCAB + col;
  float a[2][4] = {};
  for (int t = 0; t < 8; t++) {
    float4 wb[8];
    #pragma unroll
    for (int i = 0; i < 8; i++)
      wb[i] = *(const float4*)(Wp + (size_t)(t*8 + i)*NVOCAB);
    #pragma unroll
    for (int i = 0; i < 8; i++) {
      int rr = rs*64 + t*8 + i;
      float x0 = nf[rr], x1 = nf[DIM+rr];
      a[0][0] += x0*wb[i].x; a[0][1] += x0*wb[i].y; a[0][2] += x0*wb[i].z; a[0][3] += x0*wb[i].w;
      a[1][0] += x1*wb[i].x; a[1][1] += x1*wb[i].y; a[1][2] += x1*wb[i].z; a[1][3] += x1*wb[i].w;
    }
  }
  float* rp = red + tid*9;
  #pragma unroll
  for (int e = 0; e < 4; e++) { rp[e] = a[0][e]; rp[4+e] = a[1][e]; }
  __syncthreads();
  if (tid < 16) {
    float o[8] = {};
    #pragma unroll
    for (int j = 0; j < 16; j++) {
      const float* qq = red + (size_t)(j*16 + tid)*9;
      #pragma unroll
      for (int e = 0; e < 8; e++) o[e] += qq[e];
    }
    int cg = blockIdx.x*64 + tid*4;
    #pragma unroll
    for (int e = 0; e < 4; e++) {
      out[cg + e] = o[e];
      out[NVOCAB + cg + e] = o[4+e];
    }
  }
}

extern "C" void kernel_launch(void* const* d_in, const int* in_sizes, int n_in,
                              void* d_out, int out_size, void* d_ws, size_t ws_size,
                              hipStream_t stream) {
  (void)in_sizes; (void)n_in; (void)out_size; (void)ws_size;
  const float* embeds = (const float*)d_in[0];
  const int*   posids = (const int*)d_in[1];
  const float* pastK  = (const float*)d_in[2];
  const float* pastV  = (const float*)d_in[3];
  const float* Wq     = (const float*)d_in[4];
  const float* Wk     = (const float*)d_in[5];
  const float* Wv     = (const float*)d_in[6];
  const float* Wo     = (const float*)d_in[7];
  const float* Wg     = (const float*)d_in[8];
  const float* Wu     = (const float*)d_in[9];
  const float* Wd     = (const float*)d_in[10];
  const float* ln1    = (const float*)d_in[11];
  const float* ln2    = (const float*)d_in[12];
  const float* qnw    = (const float*)d_in[13];
  const float* knw    = (const float*)d_in[14];
  const float* fnw    = (const float*)d_in[15];
  const float* lmw    = (const float*)d_in[16];
  float* out = (float*)d_out;
  float* ws  = (float*)d_ws;

  k0_init<<<1, 256, 0, stream>>>(embeds, ln1, ws);
  for (int l = 0; l < NL; l++) {
    k1_qkv <<<dim3(64, 8), 256, 0, stream>>>(Wq, Wk, Wv, ln1, ws, l);
    k2_attn<<<dim3(SCH, NHKV, NB), 256, 0, stream>>>(pastK, pastV, posids, qnw, knw, out, ws, l);
    k3_wo  <<<dim3(32, 8), 256, 0, stream>>>(Wo, ws, l);
    k4_mlp1<<<dim3(48, 8), 256, 0, stream>>>(Wg, Wu, ln2, ws, l);
    k5_mlp2<<<dim3(32, 8), 256, 0, stream>>>(Wd, ws, l);
  }
  k6_lmhead<<<NVOCAB/64, 256, 0, stream>>>(lmw, fnw, ws, out);
}

// Round 6
// 1321.290 us; speedup vs baseline: 4.2328x; 1.0641x over previous
//
#include <hip/hip_runtime.h>
#include <math.h>

#define NL 28
#define DIM 1024
#define NHQ 16
#define NHKV 8
#define HDIM 128
#define NG 2
#define NFF 3072
#define NVOCAB 151936
#define NB 2
#define NPAST 1024
#define NPTOT 1025
#define EPSF 1e-6f
#define QKSCALE 0.08838834764831845f
#define LOGTHETA 13.815510557964274f

#define SQKV 8
#define SCH 32
#define NCOPY 128          // copy blocks appended to k1

// ws offsets (floats)
#define OFF_N1   0        // [NB][1024]: n1 (layer0) / final nf (after kf_final)
#define OFF_H    2048     // [NB][1024] residual h entering current layer
#define OFF_H1   4096     // [NB][1024] h after attn residual
#define OFF_QKV  8192     // [8][NB][4096] qkv partials
#define OFF_AM   73728    // [NB*16][32] chunk max
#define OFF_AL   74752    // [NB*16][32] chunk sumexp
#define OFF_AO   75776    // [NB*16][32][128] chunk weighted-V
#define OFF_WO   206848   // [8][NB][1024] Wo partials
#define OFF_G    223232   // [8][NB][3072]
#define OFF_U    272384   // [8][NB][3072]
#define OFF_WD   321536   // [8][NB][1024]

#define PK_OFF ((size_t)NB*NVOCAB)
#define PV_OFF (PK_OFF + (size_t)NL*NB*NHKV*NPTOT*HDIM)
#define PK4 (PK_OFF/4)
#define PV4 (PV_OFF/4)

__device__ __forceinline__ float wave_red_sum(float v) {
  #pragma unroll
  for (int off = 32; off > 0; off >>= 1) v += __shfl_xor(v, off);
  return v;
}

// ---------------- K0: n1 = rmsnorm(embeds)*ln1[0]; h = embeds -----------------
__global__ __launch_bounds__(256) void k0_init(const float* __restrict__ embeds,
    const float* __restrict__ ln1, float* __restrict__ ws)
{
  int tid = threadIdx.x;
  int lane = tid & 63, w = tid >> 6;
  __shared__ float wr[8];
  int d = tid*4;
  float4 v0 = *(const float4*)(embeds + d);
  float4 v1 = *(const float4*)(embeds + DIM + d);
  float4 lw = *(const float4*)(ln1 + d);
  *(float4*)(ws + OFF_H + d) = v0;
  *(float4*)(ws + OFF_H + DIM + d) = v1;
  float s0 = wave_red_sum(v0.x*v0.x + v0.y*v0.y + v0.z*v0.z + v0.w*v0.w);
  float s1 = wave_red_sum(v1.x*v1.x + v1.y*v1.y + v1.z*v1.z + v1.w*v1.w);
  if (lane == 0) { wr[w] = s0; wr[4+w] = s1; }
  __syncthreads();
  float r0 = rsqrtf((wr[0]+wr[1]+wr[2]+wr[3])/DIM + EPSF);
  float r1 = rsqrtf((wr[4]+wr[5]+wr[6]+wr[7])/DIM + EPSF);
  float4 n0 = make_float4(v0.x*r0*lw.x, v0.y*r0*lw.y, v0.z*r0*lw.z, v0.w*r0*lw.w);
  float4 n1 = make_float4(v1.x*r1*lw.x, v1.y*r1*lw.y, v1.z*r1*lw.z, v1.w*r1*lw.w);
  *(float4*)(ws + OFF_N1 + d) = n0;
  *(float4*)(ws + OFF_N1 + DIM + d) = n1;
}

// ---------------- K1: QKV GEMV partials + bonus past-KV copy blocks -----------
// grid 512+NCOPY 1D, 256 threads
__global__ __launch_bounds__(256) void k1_qkv(
    const float* __restrict__ Wq_, const float* __restrict__ Wk_,
    const float* __restrict__ Wv_, const float* __restrict__ ln1,
    const float* __restrict__ pastK, const float* __restrict__ pastV,
    float* __restrict__ out, float* __restrict__ ws, int l)
{
  int bid = blockIdx.x;
  int tid = threadIdx.x;
  if (bid >= 512) {
    // ---- dependency-free past-KV copy: pastK/V[l] -> out present region ----
    int cb = bid - 512;
    const float4* pk4 = (const float4*)pastK;
    const float4* pv4 = (const float4*)pastV;
    float4* o4 = (float4*)out;
    #pragma unroll
    for (int t = 0; t < 16; t++) {
      size_t idx = (size_t)(t*NCOPY + cb)*256 + tid;   // 0 .. 524287
      size_t pair = idx >> 15, j = idx & 32767;        // pair = b*8+kv
      size_t sbase = ((size_t)l*16 + pair)*32768 + j;  // NPAST*HDIM/4 = 32768
      size_t dbase = ((size_t)l*16 + pair)*32800 + j;  // NPTOT*HDIM/4 = 32800
      o4[PK4 + dbase] = pk4[sbase];
      o4[PV4 + dbase] = pv4[sbase];
    }
    return;
  }
  int bx = bid & 63, by = bid >> 6;
  int lane = tid & 63, w = tid >> 6;
  __shared__ __align__(16) float sh[NB][128];
  __shared__ __align__(16) float red[256*9];
  __shared__ float wr[8];

  int ct = tid & 15, rs = tid >> 4;
  int colg = bx*64 + ct*4;
  const float* W; int O; int wcol;
  if (bx < 32)      { W = Wq_; O = 2048; wcol = colg; }
  else if (bx < 48) { W = Wk_; O = 1024; wcol = colg - 2048; }
  else              { W = Wv_; O = 1024; wcol = colg - 3072; }
  int r0 = rs*8;
  const float* Wp = W + (size_t)l*DIM*O + (size_t)(by*128 + r0)*O + wcol;
  float4 wb[8];

  if (l == 0) {
    int b = tid >> 7, r = tid & 127;
    float nv = ws[OFF_N1 + b*DIM + by*128 + r];
    __builtin_amdgcn_sched_barrier(0);
    #pragma unroll
    for (int i = 0; i < 8; i++) wb[i] = *(const float4*)(Wp + (size_t)i*O);
    sh[b][r] = nv;
    __syncthreads();
  } else {
    int d = tid*4;
    float4 a0 = *(const float4*)(ws + OFF_H1 + d);
    float4 a1 = *(const float4*)(ws + OFF_H1 + DIM + d);
    #pragma unroll
    for (int s = 0; s < 8; s++) {
      float4 p0 = *(const float4*)(ws + OFF_WD + (s*NB + 0)*DIM + d);
      float4 p1 = *(const float4*)(ws + OFF_WD + (s*NB + 1)*DIM + d);
      a0.x += p0.x; a0.y += p0.y; a0.z += p0.z; a0.w += p0.w;
      a1.x += p1.x; a1.y += p1.y; a1.z += p1.z; a1.w += p1.w;
    }
    float4 lw = *(const float4*)(ln1 + (size_t)l*DIM + d);
    __builtin_amdgcn_sched_barrier(0);
    #pragma unroll
    for (int i = 0; i < 8; i++) wb[i] = *(const float4*)(Wp + (size_t)i*O);
    if (bx == 0 && by == 0) {
      *(float4*)(ws + OFF_H + d) = a0;
      *(float4*)(ws + OFF_H + DIM + d) = a1;
    }
    float s0 = wave_red_sum(a0.x*a0.x + a0.y*a0.y + a0.z*a0.z + a0.w*a0.w);
    float s1 = wave_red_sum(a1.x*a1.x + a1.y*a1.y + a1.z*a1.z + a1.w*a1.w);
    if (lane == 0) { wr[w] = s0; wr[4+w] = s1; }
    __syncthreads();
    float rq0 = rsqrtf((wr[0]+wr[1]+wr[2]+wr[3])/DIM + EPSF);
    float rq1 = rsqrtf((wr[4]+wr[5]+wr[6]+wr[7])/DIM + EPSF);
    int r = d - by*128;
    if (r >= 0 && r < 128) {
      sh[0][r] = a0.x*rq0*lw.x; sh[0][r+1] = a0.y*rq0*lw.y;
      sh[0][r+2] = a0.z*rq0*lw.z; sh[0][r+3] = a0.w*rq0*lw.w;
      sh[1][r] = a1.x*rq1*lw.x; sh[1][r+1] = a1.y*rq1*lw.y;
      sh[1][r+2] = a1.z*rq1*lw.z; sh[1][r+3] = a1.w*rq1*lw.w;
    }
    __syncthreads();
  }

  float a[2][4] = {};
  #pragma unroll
  for (int i = 0; i < 8; i++) {
    float x0 = sh[0][r0+i], x1 = sh[1][r0+i];
    a[0][0] += x0*wb[i].x; a[0][1] += x0*wb[i].y; a[0][2] += x0*wb[i].z; a[0][3] += x0*wb[i].w;
    a[1][0] += x1*wb[i].x; a[1][1] += x1*wb[i].y; a[1][2] += x1*wb[i].z; a[1][3] += x1*wb[i].w;
  }
  float* rp = red + tid*9;
  #pragma unroll
  for (int e = 0; e < 4; e++) { rp[e] = a[0][e]; rp[4+e] = a[1][e]; }
  __syncthreads();
  if (tid < 16) {
    float o[8] = {};
    #pragma unroll
    for (int j = 0; j < 16; j++) {
      const float* q = red + (size_t)(j*16 + tid)*9;
      #pragma unroll
      for (int e = 0; e < 8; e++) o[e] += q[e];
    }
    int cg = bx*64 + tid*4;
    #pragma unroll
    for (int e = 0; e < 4; e++) {
      ws[OFF_QKV + (by*NB + 0)*4096 + cg + e] = o[e];
      ws[OFF_QKV + (by*NB + 1)*4096 + cg + e] = o[4+e];
    }
  }
}

// ---------------- K2: qkv finalize + qknorm + rope + attention (reads past KV,
//                      writes only the new-token row; past copy is in K1) ------
// grid (32 chunks, NHKV, NB), 256 threads
__global__ __launch_bounds__(256) void k2_attn(
    const float* __restrict__ pastK, const float* __restrict__ pastV,
    const int* __restrict__ posids, const float* __restrict__ qnw,
    const float* __restrict__ knw, float* __restrict__ out,
    float* __restrict__ ws, int l)
{
  int c = blockIdx.x, kv = blockIdx.y, b = blockIdx.z;
  int tid = threadIdx.x;
  int lane = tid & 63, w = tid >> 6;
  int g = tid >> 7, o = tid & 127;
  __shared__ __align__(16) float qf[NG][HDIM];
  __shared__ __align__(16) float kf[HDIM];
  __shared__ __align__(16) float vf[HDIM];
  __shared__ __align__(16) float pre[NG][HDIM];
  __shared__ __align__(16) float kpre[HDIM];
  __shared__ __align__(16) float po[8][NG][HDIM];
  __shared__ float wr[8];
  __shared__ float pm[8][NG], pl[8][NG];

  // (a) preamble loads: qkv partials + norm weights + pos
  int hq = kv*NG + g;
  float qp = 0.f, kp = 0.f;
  #pragma unroll
  for (int s = 0; s < SQKV; s++) qp += ws[OFF_QKV + (s*NB + b)*4096 + hq*HDIM + o];
  int kvslot = g ? 3072 : 2048;
  #pragma unroll
  for (int s = 0; s < SQKV; s++) kp += ws[OFF_QKV + (s*NB + b)*4096 + kvslot + kv*HDIM + o];
  float qw_ = qnw[l*HDIM + o];
  float kw_ = knw[l*HDIM + o];
  float pos = (float)posids[b];
  __builtin_amdgcn_sched_barrier(0);

  // (b) KV prefetch: exactly 4 positions per 32-lane group, all past (static)
  int grp = tid >> 5, q = tid & 31;
  int p0 = c*32;
  size_t pastb4 = ((((size_t)l*NB + b)*NHKV + kv)*NPAST)*(HDIM/4);
  size_t presbase = ((((size_t)l*NB + b)*NHKV + kv)*NPTOT)*HDIM;
  const float4* pk4 = (const float4*)pastK;
  const float4* pv4 = (const float4*)pastV;
  float4 kk[4], vv[4];
  #pragma unroll
  for (int i = 0; i < 4; i++) {
    size_t p = p0 + grp + i*8;
    kk[i] = pk4[pastb4 + p*(HDIM/4) + q];
    vv[i] = pv4[pastb4 + p*(HDIM/4) + q];
  }
  __builtin_amdgcn_sched_barrier(0);

  // (c) preamble compute: qknorm + rope (overlaps KV stream)
  float sq = wave_red_sum(qp*qp);
  float sk = wave_red_sum(kp*kp);
  if (lane == 0) { wr[w] = sq; wr[4+w] = sk; }
  __syncthreads();
  float qr = rsqrtf((wr[g<<1] + wr[(g<<1)+1])/HDIM + EPSF);
  float kr = rsqrtf((wr[4] + wr[5])/HDIM + EPSF);
  float qn = qp*qr*qw_;
  pre[g][o] = qn;
  if (g == 0) kpre[o] = kp*kr*kw_;
  else vf[o] = kp;
  __syncthreads();
  float ang = pos * expf(-(2.0f*(float)(o & 63)/(float)HDIM)*LOGTHETA);
  float sn, cs;
  sincosf(ang, &sn, &cs);
  {
    float rotq = (o < 64) ? -pre[g][o+64] : pre[g][o-64];
    qf[g][o] = qn*cs + rotq*sn;
    if (g == 0) {
      float kx = kpre[o];
      float rotk = (o < 64) ? -kpre[o+64] : kpre[o-64];
      kf[o] = kx*cs + rotk*sn;
    }
  }
  __syncthreads();

  // (d) scores (static) + optional new-token term for the last chunk
  float4 q0 = *(const float4*)&qf[0][q*4];
  float4 q1 = *(const float4*)&qf[1][q*4];
  float sc0[4], sc1[4];
  #pragma unroll
  for (int i = 0; i < 4; i++) {
    float d0 = q0.x*kk[i].x + q0.y*kk[i].y + q0.z*kk[i].z + q0.w*kk[i].w;
    float d1 = q1.x*kk[i].x + q1.y*kk[i].y + q1.z*kk[i].z + q1.w*kk[i].w;
    #pragma unroll
    for (int off = 16; off > 0; off >>= 1) {
      d0 += __shfl_xor(d0, off);
      d1 += __shfl_xor(d1, off);
    }
    sc0[i] = d0*QKSCALE; sc1[i] = d1*QKSCALE;
  }
  float xs0 = -1e30f, xs1 = -1e30f;
  float4 xv = make_float4(0.f, 0.f, 0.f, 0.f);
  if (c == SCH-1 && grp == 0) {
    float4 kX = *(const float4*)&kf[q*4];
    xv = *(const float4*)&vf[q*4];
    *(float4*)(out + PK_OFF + presbase + (size_t)NPAST*HDIM + q*4) = kX;
    *(float4*)(out + PV_OFF + presbase + (size_t)NPAST*HDIM + q*4) = xv;
    float d0 = q0.x*kX.x + q0.y*kX.y + q0.z*kX.z + q0.w*kX.w;
    float d1 = q1.x*kX.x + q1.y*kX.y + q1.z*kX.z + q1.w*kX.w;
    #pragma unroll
    for (int off = 16; off > 0; off >>= 1) {
      d0 += __shfl_xor(d0, off);
      d1 += __shfl_xor(d1, off);
    }
    xs0 = d0*QKSCALE; xs1 = d1*QKSCALE;
  }
  float m0 = fmaxf(fmaxf(sc0[0], sc0[1]), fmaxf(sc0[2], sc0[3]));
  float m1 = fmaxf(fmaxf(sc1[0], sc1[1]), fmaxf(sc1[2], sc1[3]));
  m0 = fmaxf(m0, xs0); m1 = fmaxf(m1, xs1);
  if (q == 0) { pm[grp][0] = m0; pm[grp][1] = m1; }
  __syncthreads();
  float M0 = -1e30f, M1 = -1e30f;
  #pragma unroll
  for (int j = 0; j < 8; j++) { M0 = fmaxf(M0, pm[j][0]); M1 = fmaxf(M1, pm[j][1]); }
  float l0 = 0.f, l1 = 0.f;
  float4 o0 = {0,0,0,0}, o1 = {0,0,0,0};
  #pragma unroll
  for (int j = 0; j < 4; j++) {
    float w0 = __expf(sc0[j] - M0), w1 = __expf(sc1[j] - M1);
    l0 += w0; l1 += w1;
    o0.x += w0*vv[j].x; o0.y += w0*vv[j].y; o0.z += w0*vv[j].z; o0.w += w0*vv[j].w;
    o1.x += w1*vv[j].x; o1.y += w1*vv[j].y; o1.z += w1*vv[j].z; o1.w += w1*vv[j].w;
  }
  { // new-token term: exp(-1e30 - M) == 0 for all non-participating lanes/chunks
    float w0 = __expf(xs0 - M0), w1 = __expf(xs1 - M1);
    l0 += w0; l1 += w1;
    o0.x += w0*xv.x; o0.y += w0*xv.y; o0.z += w0*xv.z; o0.w += w0*xv.w;
    o1.x += w1*xv.x; o1.y += w1*xv.y; o1.z += w1*xv.z; o1.w += w1*xv.w;
  }
  if (q == 0) { pl[grp][0] = l0; pl[grp][1] = l1; }
  *(float4*)&po[grp][0][q*4] = o0;
  *(float4*)&po[grp][1][q*4] = o1;
  __syncthreads();
  {
    int head = tid >> 7, dd = tid & 127;
    float acc = 0.f;
    #pragma unroll
    for (int j = 0; j < 8; j++) acc += po[j][head][dd];
    int base = ((b*NHKV + kv)*NG + head)*SCH + c;
    ws[OFF_AO + (size_t)base*HDIM + dd] = acc;
    if (dd == 0) {
      float ll = 0.f;
      #pragma unroll
      for (int j = 0; j < 8; j++) ll += pl[j][head];
      ws[OFF_AM + base] = (head ? M1 : M0);
      ws[OFF_AL + base] = ll;
    }
  }
}

// ---------------- K3: softmax combine + Wo GEMV partials ----------------------
// grid (32 colTiles(32), 8 headPairs(256 rows)), 256 threads
__global__ __launch_bounds__(256) void k3_wo(const float* __restrict__ Wo_,
    float* __restrict__ ws, int l)
{
  int bx = blockIdx.x, by = blockIdx.y;
  int tid = threadIdx.x;
  __shared__ __align__(16) float x[NB][256];
  __shared__ float wf[NB][2][SCH];
  __shared__ float invL[NB][2];
  __shared__ __align__(16) float red[256*9];

  if (tid < 128) {
    int b = tid >> 6, hh = (tid >> 5) & 1, cc = tid & 31;
    int hb = b*16 + by*2 + hh;
    float m  = ws[OFF_AM + hb*SCH + cc];
    float ll = ws[OFF_AL + hb*SCH + cc];
    float M = m;
    #pragma unroll
    for (int off = 16; off > 0; off >>= 1) M = fmaxf(M, __shfl_xor(M, off));
    float f = __expf(m - M);
    float Ls = ll*f;
    #pragma unroll
    for (int off = 16; off > 0; off >>= 1) Ls += __shfl_xor(Ls, off);
    wf[b][hh][cc] = f;
    if (cc == 0) invL[b][hh] = 1.0f/Ls;
  }
  __builtin_amdgcn_sched_barrier(0);

  int ct = tid & 7, rs = tid >> 3;
  int col = bx*32 + ct*4;
  int r0 = rs*8;
  const float* Wp = Wo_ + (size_t)l*(NHQ*HDIM)*DIM + (size_t)(by*256 + r0)*DIM + col;
  float4 wb[8];
  #pragma unroll
  for (int i = 0; i < 8; i++) wb[i] = *(const float4*)(Wp + (size_t)i*DIM);
  __syncthreads();

  for (int e = tid; e < 512; e += 256) {
    int b = e >> 8, rr = e & 255, hh = rr >> 7, dd = rr & 127;
    int hb = b*16 + by*2 + hh;
    const float* op = ws + OFF_AO + (size_t)(hb*SCH)*HDIM + dd;
    float acc = 0.f;
    #pragma unroll
    for (int cc = 0; cc < SCH; cc++) acc += op[(size_t)cc*HDIM]*wf[b][hh][cc];
    x[b][rr] = acc*invL[b][hh];
  }
  __syncthreads();
  float a[2][4] = {};
  #pragma unroll
  for (int i = 0; i < 8; i++) {
    float x0 = x[0][r0+i], x1 = x[1][r0+i];
    a[0][0] += x0*wb[i].x; a[0][1] += x0*wb[i].y; a[0][2] += x0*wb[i].z; a[0][3] += x0*wb[i].w;
    a[1][0] += x1*wb[i].x; a[1][1] += x1*wb[i].y; a[1][2] += x1*wb[i].z; a[1][3] += x1*wb[i].w;
  }
  float* rp = red + tid*9;
  #pragma unroll
  for (int e = 0; e < 4; e++) { rp[e] = a[0][e]; rp[4+e] = a[1][e]; }
  __syncthreads();
  if (tid < 8) {
    float o[8] = {};
    #pragma unroll
    for (int j = 0; j < 32; j++) {
      const float* qq = red + (size_t)(j*8 + tid)*9;
      #pragma unroll
      for (int e = 0; e < 8; e++) o[e] += qq[e];
    }
    int cg = bx*32 + tid*4;
    #pragma unroll
    for (int e = 0; e < 4; e++) {
      ws[OFF_WO + (by*NB + 0)*DIM + cg + e] = o[e];
      ws[OFF_WO + (by*NB + 1)*DIM + cg + e] = o[4+e];
    }
  }
}

// ---------------- K4: h1+n2 recompute + Wg/Wu GEMV partials -------------------
// grid (48 colTiles(64), 8 rowSplits(128)), 256 threads
__global__ __launch_bounds__(256) void k4_mlp1(const float* __restrict__ Wg_,
    const float* __restrict__ Wu_, const float* __restrict__ ln2,
    float* __restrict__ ws, int l)
{
  int bx = blockIdx.x, by = blockIdx.y;
  int tid = threadIdx.x;
  int lane = tid & 63, w = tid >> 6;
  __shared__ __align__(16) float sh[NB][128];
  __shared__ __align__(16) float red[256*9];
  __shared__ float wr[8];

  int d = tid*4;
  float4 a0 = *(const float4*)(ws + OFF_H + d);
  float4 a1 = *(const float4*)(ws + OFF_H + DIM + d);
  #pragma unroll
  for (int s = 0; s < 8; s++) {
    float4 p0 = *(const float4*)(ws + OFF_WO + (s*NB + 0)*DIM + d);
    float4 p1 = *(const float4*)(ws + OFF_WO + (s*NB + 1)*DIM + d);
    a0.x += p0.x; a0.y += p0.y; a0.z += p0.z; a0.w += p0.w;
    a1.x += p1.x; a1.y += p1.y; a1.z += p1.z; a1.w += p1.w;
  }
  float4 lw = *(const float4*)(ln2 + (size_t)l*DIM + d);
  __builtin_amdgcn_sched_barrier(0);

  int ct = tid & 15, rs = tid >> 4;
  int col = bx*64 + ct*4;
  int r0 = rs*8;
  const float* Wgp = Wg_ + (size_t)l*DIM*NFF + (size_t)(by*128 + r0)*NFF + col;
  const float* Wup = Wu_ + (size_t)l*DIM*NFF + (size_t)(by*128 + r0)*NFF + col;
  float4 wg[8], wu[8];
  #pragma unroll
  for (int i = 0; i < 8; i++) {
    wg[i] = *(const float4*)(Wgp + (size_t)i*NFF);
    wu[i] = *(const float4*)(Wup + (size_t)i*NFF);
  }

  if (bx == 0 && by == 0) {
    *(float4*)(ws + OFF_H1 + d) = a0;
    *(float4*)(ws + OFF_H1 + DIM + d) = a1;
  }
  float s0 = wave_red_sum(a0.x*a0.x + a0.y*a0.y + a0.z*a0.z + a0.w*a0.w);
  float s1 = wave_red_sum(a1.x*a1.x + a1.y*a1.y + a1.z*a1.z + a1.w*a1.w);
  if (lane == 0) { wr[w] = s0; wr[4+w] = s1; }
  __syncthreads();
  float rq0 = rsqrtf((wr[0]+wr[1]+wr[2]+wr[3])/DIM + EPSF);
  float rq1 = rsqrtf((wr[4]+wr[5]+wr[6]+wr[7])/DIM + EPSF);
  int r = d - by*128;
  if (r >= 0 && r < 128) {
    sh[0][r] = a0.x*rq0*lw.x; sh[0][r+1] = a0.y*rq0*lw.y;
    sh[0][r+2] = a0.z*rq0*lw.z; sh[0][r+3] = a0.w*rq0*lw.w;
    sh[1][r] = a1.x*rq1*lw.x; sh[1][r+1] = a1.y*rq1*lw.y;
    sh[1][r+2] = a1.z*rq1*lw.z; sh[1][r+3] = a1.w*rq1*lw.w;
  }
  __syncthreads();

  float ag[2][4] = {}, au[2][4] = {};
  #pragma unroll
  for (int i = 0; i < 8; i++) {
    float x0 = sh[0][r0+i], x1 = sh[1][r0+i];
    ag[0][0] += x0*wg[i].x; ag[0][1] += x0*wg[i].y; ag[0][2] += x0*wg[i].z; ag[0][3] += x0*wg[i].w;
    ag[1][0] += x1*wg[i].x; ag[1][1] += x1*wg[i].y; ag[1][2] += x1*wg[i].z; ag[1][3] += x1*wg[i].w;
    au[0][0] += x0*wu[i].x; au[0][1] += x0*wu[i].y; au[0][2] += x0*wu[i].z; au[0][3] += x0*wu[i].w;
    au[1][0] += x1*wu[i].x; au[1][1] += x1*wu[i].y; au[1][2] += x1*wu[i].z; au[1][3] += x1*wu[i].w;
  }
  float* rp = red + tid*9;
  #pragma unroll
  for (int e = 0; e < 4; e++) { rp[e] = ag[0][e]; rp[4+e] = ag[1][e]; }
  __syncthreads();
  if (tid < 16) {
    float o[8] = {};
    #pragma unroll
    for (int j = 0; j < 16; j++) {
      const float* qq = red + (size_t)(j*16 + tid)*9;
      #pragma unroll
      for (int e = 0; e < 8; e++) o[e] += qq[e];
    }
    int cg = bx*64 + tid*4;
    #pragma unroll
    for (int e = 0; e < 4; e++) {
      ws[OFF_G + (by*NB + 0)*NFF + cg + e] = o[e];
      ws[OFF_G + (by*NB + 1)*NFF + cg + e] = o[4+e];
    }
  }
  __syncthreads();
  #pragma unroll
  for (int e = 0; e < 4; e++) { rp[e] = au[0][e]; rp[4+e] = au[1][e]; }
  __syncthreads();
  if (tid < 16) {
    float o[8] = {};
    #pragma unroll
    for (int j = 0; j < 16; j++) {
      const float* qq = red + (size_t)(j*16 + tid)*9;
      #pragma unroll
      for (int e = 0; e < 8; e++) o[e] += qq[e];
    }
    int cg = bx*64 + tid*4;
    #pragma unroll
    for (int e = 0; e < 4; e++) {
      ws[OFF_U + (by*NB + 0)*NFF + cg + e] = o[e];
      ws[OFF_U + (by*NB + 1)*NFF + cg + e] = o[4+e];
    }
  }
}

// ---------------- K5: swiglu slice + Wd GEMV partials -------------------------
// grid (32 colTiles(32), 8 ffSplits(384)), 256 threads
__global__ __launch_bounds__(256) void k5_mlp2(const float* __restrict__ Wd_,
    float* __restrict__ ws, int l)
{
  int bx = blockIdx.x, by = blockIdx.y;
  int tid = threadIdx.x;
  __shared__ __align__(16) float act[NB][384];
  __shared__ __align__(16) float red[256*9];

  float4 gacc = {0,0,0,0}, uacc = {0,0,0,0};
  int pb = 0, pf4 = 0;
  if (tid < 192) {
    pb = tid / 96; pf4 = tid % 96;
    int f4 = (by*384)/4 + pf4;
    const float4* Gp = (const float4*)(ws + OFF_G);
    const float4* Up = (const float4*)(ws + OFF_U);
    #pragma unroll
    for (int s = 0; s < 8; s++) {
      float4 g4 = Gp[(size_t)(s*NB + pb)*(NFF/4) + f4];
      float4 u4 = Up[(size_t)(s*NB + pb)*(NFF/4) + f4];
      gacc.x += g4.x; gacc.y += g4.y; gacc.z += g4.z; gacc.w += g4.w;
      uacc.x += u4.x; uacc.y += u4.y; uacc.z += u4.z; uacc.w += u4.w;
    }
  }
  __builtin_amdgcn_sched_barrier(0);

  int ct = tid & 7, rs = tid >> 3;
  int col = bx*32 + ct*4;
  int r0 = rs*12;
  const float* Wp = Wd_ + (size_t)l*NFF*DIM + (size_t)(by*384 + r0)*DIM + col;
  float4 wb[12];
  #pragma unroll
  for (int i = 0; i < 12; i++) wb[i] = *(const float4*)(Wp + (size_t)i*DIM);

  if (tid < 192) {
    float4 r;
    r.x = (gacc.x / (1.0f + __expf(-gacc.x)))*uacc.x;
    r.y = (gacc.y / (1.0f + __expf(-gacc.y)))*uacc.y;
    r.z = (gacc.z / (1.0f + __expf(-gacc.z)))*uacc.z;
    r.w = (gacc.w / (1.0f + __expf(-gacc.w)))*uacc.w;
    *(float4*)&act[pb][pf4*4] = r;
  }
  __syncthreads();

  float a[2][4] = {};
  #pragma unroll
  for (int i = 0; i < 12; i++) {
    float x0 = act[0][r0+i], x1 = act[1][r0+i];
    a[0][0] += x0*wb[i].x; a[0][1] += x0*wb[i].y; a[0][2] += x0*wb[i].z; a[0][3] += x0*wb[i].w;
    a[1][0] += x1*wb[i].x; a[1][1] += x1*wb[i].y; a[1][2] += x1*wb[i].z; a[1][3] += x1*wb[i].w;
  }
  float* rp = red + tid*9;
  #pragma unroll
  for (int e = 0; e < 4; e++) { rp[e] = a[0][e]; rp[4+e] = a[1][e]; }
  __syncthreads();
  if (tid < 8) {
    float o[8] = {};
    #pragma unroll
    for (int j = 0; j < 32; j++) {
      const float* qq = red + (size_t)(j*8 + tid)*9;
      #pragma unroll
      for (int e = 0; e < 8; e++) o[e] += qq[e];
    }
    int cg = bx*32 + tid*4;
    #pragma unroll
    for (int e = 0; e < 4; e++) {
      ws[OFF_WD + (by*NB + 0)*DIM + cg + e] = o[e];
      ws[OFF_WD + (by*NB + 1)*DIM + cg + e] = o[4+e];
    }
  }
}

// ---------------- KF: finalize h2 + final rmsnorm -> nf (1 block) -------------
__global__ __launch_bounds__(256) void kf_final(const float* __restrict__ fnw,
    float* __restrict__ ws)
{
  int tid = threadIdx.x;
  int lane = tid & 63, w = tid >> 6;
  __shared__ float wr[8];
  int d = tid*4;
  float4 a0 = *(const float4*)(ws + OFF_H1 + d);
  float4 a1 = *(const float4*)(ws + OFF_H1 + DIM + d);
  #pragma unroll
  for (int s = 0; s < 8; s++) {
    float4 p0 = *(const float4*)(ws + OFF_WD + (s*NB + 0)*DIM + d);
    float4 p1 = *(const float4*)(ws + OFF_WD + (s*NB + 1)*DIM + d);
    a0.x += p0.x; a0.y += p0.y; a0.z += p0.z; a0.w += p0.w;
    a1.x += p1.x; a1.y += p1.y; a1.z += p1.z; a1.w += p1.w;
  }
  float4 fw = *(const float4*)(fnw + d);
  float s0 = wave_red_sum(a0.x*a0.x + a0.y*a0.y + a0.z*a0.z + a0.w*a0.w);
  float s1 = wave_red_sum(a1.x*a1.x + a1.y*a1.y + a1.z*a1.z + a1.w*a1.w);
  if (lane == 0) { wr[w] = s0; wr[4+w] = s1; }
  __syncthreads();
  float rq0 = rsqrtf((wr[0]+wr[1]+wr[2]+wr[3])/DIM + EPSF);
  float rq1 = rsqrtf((wr[4]+wr[5]+wr[6]+wr[7])/DIM + EPSF);
  float4 n0 = make_float4(a0.x*rq0*fw.x, a0.y*rq0*fw.y, a0.z*rq0*fw.z, a0.w*rq0*fw.w);
  float4 n1 = make_float4(a1.x*rq1*fw.x, a1.y*rq1*fw.y, a1.z*rq1*fw.z, a1.w*rq1*fw.w);
  *(float4*)(ws + OFF_N1 + d) = n0;
  *(float4*)(ws + OFF_N1 + DIM + d) = n1;
}

// ---------------- K6: lm_head GEMV (nf precomputed) ---------------------------
// grid 2374 blocks (64 cols each), 256 threads
__global__ __launch_bounds__(256) void k6_lmhead(const float* __restrict__ lmw,
    const float* __restrict__ ws, float* __restrict__ out)
{
  __shared__ __align__(16) float nf[NB*DIM];
  __shared__ __align__(16) float red[256*9];
  int tid = threadIdx.x;
  *(float4*)&nf[tid*4]        = *(const float4*)(ws + OFF_N1 + tid*4);
  *(float4*)&nf[1024 + tid*4] = *(const float4*)(ws + OFF_N1 + 1024 + tid*4);
  __syncthreads();

  int ct = tid & 15, rs = tid >> 4;
  int col = blockIdx.x*64 + ct*4;
  const float* Wp = lmw + (size_t)(rs*64)*NVOCAB + col;
  float a[2][4] = {};
  for (int t = 0; t < 8; t++) {
    float4 wb[8];
    #pragma unroll
    for (int i = 0; i < 8; i++)
      wb[i] = *(const float4*)(Wp + (size_t)(t*8 + i)*NVOCAB);
    #pragma unroll
    for (int i = 0; i < 8; i++) {
      int rr = rs*64 + t*8 + i;
      float x0 = nf[rr], x1 = nf[DIM+rr];
      a[0][0] += x0*wb[i].x; a[0][1] += x0*wb[i].y; a[0][2] += x0*wb[i].z; a[0][3] += x0*wb[i].w;
      a[1][0] += x1*wb[i].x; a[1][1] += x1*wb[i].y; a[1][2] += x1*wb[i].z; a[1][3] += x1*wb[i].w;
    }
  }
  float* rp = red + tid*9;
  #pragma unroll
  for (int e = 0; e < 4; e++) { rp[e] = a[0][e]; rp[4+e] = a[1][e]; }
  __syncthreads();
  if (tid < 16) {
    float o[8] = {};
    #pragma unroll
    for (int j = 0; j < 16; j++) {
      const float* qq = red + (size_t)(j*16 + tid)*9;
      #pragma unroll
      for (int e = 0; e < 8; e++) o[e] += qq[e];
    }
    int cg = blockIdx.x*64 + tid*4;
    #pragma unroll
    for (int e = 0; e < 4; e++) {
      out[cg + e] = o[e];
      out[NVOCAB + cg + e] = o[4+e];
    }
  }
}

extern "C" void kernel_launch(void* const* d_in, const int* in_sizes, int n_in,
                              void* d_out, int out_size, void* d_ws, size_t ws_size,
                              hipStream_t stream) {
  (void)in_sizes; (void)n_in; (void)out_size; (void)ws_size;
  const float* embeds = (const float*)d_in[0];
  const int*   posids = (const int*)d_in[1];
  const float* pastK  = (const float*)d_in[2];
  const float* pastV  = (const float*)d_in[3];
  const float* Wq     = (const float*)d_in[4];
  const float* Wk     = (const float*)d_in[5];
  const float* Wv     = (const float*)d_in[6];
  const float* Wo     = (const float*)d_in[7];
  const float* Wg     = (const float*)d_in[8];
  const float* Wu     = (const float*)d_in[9];
  const float* Wd     = (const float*)d_in[10];
  const float* ln1    = (const float*)d_in[11];
  const float* ln2    = (const float*)d_in[12];
  const float* qnw    = (const float*)d_in[13];
  const float* knw    = (const float*)d_in[14];
  const float* fnw    = (const float*)d_in[15];
  const float* lmw    = (const float*)d_in[16];
  float* out = (float*)d_out;
  float* ws  = (float*)d_ws;

  k0_init<<<1, 256, 0, stream>>>(embeds, ln1, ws);
  for (int l = 0; l < NL; l++) {
    k1_qkv <<<512 + NCOPY, 256, 0, stream>>>(Wq, Wk, Wv, ln1, pastK, pastV, out, ws, l);
    k2_attn<<<dim3(SCH, NHKV, NB), 256, 0, stream>>>(pastK, pastV, posids, qnw, knw, out, ws, l);
    k3_wo  <<<dim3(32, 8), 256, 0, stream>>>(Wo, ws, l);
    k4_mlp1<<<dim3(48, 8), 256, 0, stream>>>(Wg, Wu, ln2, ws, l);
    k5_mlp2<<<dim3(32, 8), 256, 0, stream>>>(Wd, ws, l);
  }
  kf_final<<<1, 256, 0, stream>>>(fnw, ws);
  k6_lmhead<<<NVOCAB/64, 256, 0, stream>>>(lmw, ws, out);
}